// Round 13
// baseline (2476.456 us; speedup 1.0000x reference)
//
#include <hip/hip_runtime.h>

#define BB 64   // batch
#define CC 64   // channels

typedef __attribute__((ext_vector_type(8))) short short8;
typedef __attribute__((ext_vector_type(4))) short short4v;
typedef __attribute__((ext_vector_type(4))) float f32x4;

__device__ __forceinline__ float bf2f(unsigned short h) {
    unsigned int u = ((unsigned int)h) << 16;
    float f; __builtin_memcpy(&f, &u, 4); return f;
}
__device__ __forceinline__ unsigned short f2bf(float f) {
    unsigned int u; __builtin_memcpy(&u, &f, 4);
    u += 0x7fffu + ((u >> 16) & 1u);
    return (unsigned short)(u >> 16);
}

// ================= GN1 stats directly from x (recompute conv1) =================
__global__ __launch_bounds__(256) void conv1stats_kernel(const float* __restrict__ x,
    const float* __restrict__ w1, const float* __restrict__ b1,
    float* __restrict__ ps, float* __restrict__ ps2) {
    __shared__ float sw1[576];
    __shared__ float sb1[64];
    __shared__ float xs[10 * 130];
    int tid = threadIdx.x;
    int qq = blockIdx.x;
    int b = blockIdx.y;
    for (int i = tid; i < 576; i += 256) sw1[i] = w1[i];
    if (tid < 64) sb1[tid] = b1[tid];
    const float* xb = x + (size_t)b * 130 * 130;
    int c = tid >> 2, q = tid & 3;
    float s = 0.f, s2 = 0.f;
    for (int sidx = 0; sidx < 2; sidx++) {
        int row0 = (qq * 2 + sidx) * 8;
        __syncthreads();
        for (int i = tid; i < 1300; i += 256) xs[i] = xb[row0 * 130 + i];
        __syncthreads();
        const float* wc = &sw1[c * 9];
        float bc = sb1[c];
        for (int p = q; p < 1024; p += 4) {
            int y = p >> 7, xx = p & 127;
            float v = bc;
#pragma unroll
            for (int ky = 0; ky < 3; ky++)
#pragma unroll
                for (int kx = 0; kx < 3; kx++)
                    v += xs[(y + ky) * 130 + xx + kx] * wc[ky * 3 + kx];
            s += v; s2 += v * v;
        }
    }
    s  += __shfl_xor(s, 1, 64);  s  += __shfl_xor(s, 2, 64);
    s2 += __shfl_xor(s2, 1, 64); s2 += __shfl_xor(s2, 2, 64);
    if (q == 0) {
        ps [(b * 8 + qq) * 64 + c] = s;
        ps2[(b * 8 + qq) * 64 + c] = s2;
    }
}

__global__ __launch_bounds__(256) void gn1fin_kernel(const float* __restrict__ ps,
    const float* __restrict__ ps2, const float* __restrict__ n1w, const float* __restrict__ n1b,
    float* __restrict__ gn1sc, float* __restrict__ gn1sh) {
    int i = blockIdx.x * 256 + threadIdx.x;
    if (i >= BB * CC) return;
    int c = i & 63, b = i >> 6;
    float s = 0.f, s2 = 0.f;
#pragma unroll
    for (int qq = 0; qq < 8; qq++) {
        s  += ps [(b * 8 + qq) * 64 + c];
        s2 += ps2[(b * 8 + qq) * 64 + c];
    }
    float mean = s / 16384.f;
    float var = s2 / 16384.f - mean * mean;
    float rstd = rsqrtf(var + 1e-5f);
    float sc = rstd * n1w[c];
    gn1sc[i] = sc;
    gn1sh[i] = n1b[c] - mean * sc;
}

// ===== weight prepack, chunk-major A: Apk[kc][co][32] bf16 =====
__global__ __launch_bounds__(256) void prepack_kernel(const float* __restrict__ w1,
    const float* __restrict__ w2, const float* __restrict__ dw2,
    const float* __restrict__ dw3, unsigned short* __restrict__ Apk,
    float* __restrict__ Stab) {
    int set = blockIdx.y, kc = blockIdx.x, tid = threadIdx.x;
    int nchunk = (set < 2) ? 18 : 32;
    if (kc < nchunk) {
        const float* w = (set == 0) ? w1 : (set == 1) ? w2 : (set == 2) ? dw2 : dw3;
        size_t off = (set == 0) ? 0 : (set == 1) ? 36864 : (set == 2) ? 73728 : 139264;
        for (int e = tid; e < 2048; e += 256) {
            int co = e >> 5, j = e & 31;
            int k = kc * 32 + j;
            int ci = k & 63;
            int tap = k >> 6;
            float val;
            if (set < 2) val = w[(co * 65 + ci + 1) * 9 + tap];
            else         val = w[((co << 6) + ci) * 16 + tap];
            Apk[off + (size_t)kc * 2048 + e] = f2bf(val);
        }
    }
    if (set < 2 && kc == 0) {
        const float* w = set ? w2 : w1;
        for (int t = tid; t < 576; t += 256) {
            int co = t / 9, tap = t % 9;
            Stab[set * 576 + t] = w[(co * 65) * 9 + tap];
        }
    }
}

// ===== ds1: materialize h1n = relu(gn1(conv1(x))) as bf16 NHWC [B,128,128,64] =====
// grid (32, BB): block = 4 rows x 128 cols. Pure VALU + streaming write.
__global__ __launch_bounds__(256) void ds1_kernel(const float* __restrict__ x,
    const float* __restrict__ w1, const float* __restrict__ b1,
    const float* __restrict__ gn1sc, const float* __restrict__ gn1sh,
    unsigned short* __restrict__ h1n) {
    __shared__ float sw1[576];
    __shared__ float sb1[64], ssc[64], ssh[64];
    __shared__ float xs[6 * 130];
    int tid = threadIdx.x;
    int by = blockIdx.x, b = blockIdx.y;
    for (int i = tid; i < 576; i += 256) sw1[i] = w1[i];
    if (tid < 64) {
        sb1[tid] = b1[tid];
        ssc[tid] = gn1sc[b * 64 + tid];
        ssh[tid] = gn1sh[b * 64 + tid];
    }
    {
        const float* xb = x + (size_t)b * 130 * 130 + (size_t)(4 * by) * 130;
        for (int i = tid; i < 780; i += 256) xs[i] = xb[i];
    }
    __syncthreads();
    int xc = tid & 127, r0 = tid >> 7;   // 2 rows per pass, 2 passes
#pragma unroll
    for (int p = 0; p < 2; ++p) {
        int y = r0 + 2 * p;              // 0..3
        float v9[3][3];
        // gather the 3x3 input window once
#pragma unroll
        for (int ky = 0; ky < 3; ky++)
#pragma unroll
            for (int kx = 0; kx < 3; kx++)
                v9[ky][kx] = xs[(y + ky) * 130 + xc + kx];
        unsigned short* op = h1n + ((size_t)((b * 128 + 4 * by + y) * 128 + xc)) * 64;
#pragma unroll
        for (int cg = 0; cg < 8; ++cg) {
            short8 o;
#pragma unroll
            for (int e = 0; e < 8; ++e) {
                int c = cg * 8 + e;
                const float* wc = &sw1[c * 9];
                float v = sb1[c];
#pragma unroll
                for (int ky = 0; ky < 3; ky++)
#pragma unroll
                    for (int kx = 0; kx < 3; kx++)
                        v += v9[ky][kx] * wc[ky * 3 + kx];
                o[e] = (short)f2bf(fmaxf(fmaf(v, ssc[c], ssh[c]), 0.f));
            }
            *(short8*)(op + cg * 8) = o;
        }
    }
}

// ===== ds2b: h1n (ready bf16 NHWC) -> conv4x4/s2 MFMA -> h2; no recompute =====
// grid (64 = 2 xh x 32 sy, BB), block 256. GN2 partials -> sub-slot bx.
__global__ __launch_bounds__(256) void ds2b_kernel(const unsigned short* __restrict__ h1n,
    const unsigned short* __restrict__ Apk, const float* __restrict__ bias2,
    unsigned short* __restrict__ h2, float* __restrict__ sums_out) {
    __shared__ unsigned short X[2 * 198 * 64];
    __shared__ float sb2[64];
    __shared__ float sred[4][64], s2red[4][64];
    int tid = threadIdx.x;
    int b = blockIdx.y;
    int bx = blockIdx.x;
    int xh = bx & 1, sy = bx >> 1;
    int lane = tid & 63, w = tid >> 6;
    int colL = lane & 15, quad = lane >> 4;
    int sub = tid & 7;

    if (tid < 64) sb2[tid] = bias2[tid];
    for (int i = tid; i < 3168; i += 256) {
        int pidx = i >> 3;
        int ir = pidx / 66, ic = pidx - ir * 66;
        int gy = 4 * sy - 1 + ir, gxg = 64 * xh - 1 + ic;
        short8 o;
        if (gy >= 0 && gy < 128 && gxg >= 0 && gxg < 128) {
            o = *(const short8*)(h1n + ((size_t)((b * 128 + gy) * 128 + gxg)) * 64 + sub * 8);
        } else {
#pragma unroll
            for (int e = 0; e < 8; e++) o[e] = 0;
        }
        int p = ic & 1;
        int psx = ir * 33 + (ic >> 1);
        *(short8*)(X + ((p * 198 + psx) << 6) + ((sub ^ (psx & 7)) << 3)) = o;
    }
    __syncthreads();

    int l = w >> 1, oxb = (w & 1) * 16;
    int oxl = oxb + colL;
    f32x4 acc[4] = {};
    for (int kc = 0; kc < 32; ++kc) {
        int tap = kc >> 1;
        int ky = tap >> 2, kx = tap & 3;
        int chgrp = (kc & 1) * 4 + quad;
        int ir = 2 * l + ky;
        int p = kx & 1;
        int psx = ir * 33 + oxl + (kx >> 1);
        short8 bb = *(const short8*)(X + ((p * 198 + psx) << 6) + ((chgrp ^ (psx & 7)) << 3));
        const unsigned short* ap = Apk + (((kc << 6) + colL) << 5) + (quad << 3);
        short8 a0 = *(const short8*)(ap);
        short8 a1 = *(const short8*)(ap + 512);
        short8 a2 = *(const short8*)(ap + 1024);
        short8 a3 = *(const short8*)(ap + 1536);
        acc[0] = __builtin_amdgcn_mfma_f32_16x16x32_bf16(a0, bb, acc[0], 0, 0, 0);
        acc[1] = __builtin_amdgcn_mfma_f32_16x16x32_bf16(a1, bb, acc[1], 0, 0, 0);
        acc[2] = __builtin_amdgcn_mfma_f32_16x16x32_bf16(a2, bb, acc[2], 0, 0, 0);
        acc[3] = __builtin_amdgcn_mfma_f32_16x16x32_bf16(a3, bb, acc[3], 0, 0, 0);
    }

    float sl[16], s2l[16];
#pragma unroll
    for (int i = 0; i < 16; i++) { sl[i] = 0.f; s2l[i] = 0.f; }
    int oy = 2 * sy + l, oxg = xh * 32 + oxl;
#pragma unroll
    for (int mt = 0; mt < 4; ++mt) {
        int co0 = mt * 16 + quad * 4;
        size_t base = ((size_t)((b * 64 + oy) * 64 + oxg)) * 64 + co0;
        short4v o;
#pragma unroll
        for (int r = 0; r < 4; ++r) {
            unsigned short hh = f2bf(acc[mt][r] + sb2[co0 + r]);
            o[r] = (short)hh;
            float f = bf2f(hh);
            sl[mt * 4 + r] += f; s2l[mt * 4 + r] += f * f;
        }
        *(short4v*)(h2 + base) = o;
    }
#pragma unroll
    for (int idx = 0; idx < 16; ++idx) {
        float s = sl[idx], s2 = s2l[idx];
        s += __shfl_xor(s, 1, 64); s += __shfl_xor(s, 2, 64);
        s += __shfl_xor(s, 4, 64); s += __shfl_xor(s, 8, 64);
        s2 += __shfl_xor(s2, 1, 64); s2 += __shfl_xor(s2, 2, 64);
        s2 += __shfl_xor(s2, 4, 64); s2 += __shfl_xor(s2, 8, 64);
        if (colL == 0) {
            int co = (idx >> 2) * 16 + quad * 4 + (idx & 3);
            sred[w][co] = s; s2red[w][co] = s2;
        }
    }
    __syncthreads();
    if (tid < 64) {
        float s = sred[0][tid] + sred[1][tid] + sred[2][tid] + sred[3][tid];
        float s2 = s2red[0][tid] + s2red[1][tid] + s2red[2][tid] + s2red[3][tid];
        sums_out[(size_t)bx * 8192 + b * 64 + tid] = s;
        sums_out[(size_t)bx * 8192 + 4096 + b * 64 + tid] = s2;
    }
}

// ===== ds2mfma (fallback when ws too small): x -> conv1 -> GN1 -> ReLU -> conv MFMA =====
__global__ __launch_bounds__(256) void ds2mfma_kernel(const float* __restrict__ x,
    const float* __restrict__ w1, const float* __restrict__ b1,
    const float* __restrict__ gn1sc, const float* __restrict__ gn1sh,
    const unsigned short* __restrict__ Apk, const float* __restrict__ bias2,
    unsigned short* __restrict__ h2, float* __restrict__ sums_out) {
    __shared__ unsigned short X[2 * 198 * 64];
    __shared__ float xs[8 * 68];
    __shared__ float sw1[576];
    __shared__ float sb1[64], ssc[64], ssh[64], sb2[64];
    __shared__ float sred[4][64], s2red[4][64];
    int tid = threadIdx.x;
    int b = blockIdx.y;
    int bx = blockIdx.x;
    int xh = bx & 1, sy = bx >> 1;
    int lane = tid & 63, w = tid >> 6;
    int colL = lane & 15, quad = lane >> 4;

    for (int i = tid; i < 576; i += 256) sw1[i] = w1[i];
    if (tid < 64) {
        sb1[tid] = b1[tid];
        ssc[tid] = gn1sc[b * 64 + tid];
        ssh[tid] = gn1sh[b * 64 + tid];
        sb2[tid] = bias2[tid];
    }
    {
        const float* xb = x + (size_t)b * 130 * 130;
        for (int i = tid; i < 544; i += 256) {
            int r = i / 68, cc = i % 68;
            int xr = 4 * sy - 1 + r, xcg = 64 * xh - 1 + cc;
            xs[i] = (xr >= 0 && xr < 130 && xcg >= 0 && xcg < 130) ? xb[xr * 130 + xcg] : 0.f;
        }
    }
    __syncthreads();
    {
        int sub = tid & 7;
        float sbr[8], scr[8], shr[8];
#pragma unroll
        for (int e = 0; e < 8; e++) {
            int c = sub * 8 + e;
            sbr[e] = sb1[c]; scr[e] = ssc[c]; shr[e] = ssh[c];
        }
        for (int i = tid; i < 3168; i += 256) {
            int pidx = i >> 3;
            int ir = pidx / 66, ic = pidx - ir * 66;
            int gy = 4 * sy - 1 + ir, gxg = 64 * xh - 1 + ic;
            short8 o;
            if (gy >= 0 && gy < 128 && gxg >= 0 && gxg < 128) {
#pragma unroll
                for (int e = 0; e < 8; e++) {
                    int c = sub * 8 + e;
                    float v = sbr[e];
#pragma unroll
                    for (int ky = 0; ky < 3; ky++)
#pragma unroll
                        for (int kx = 0; kx < 3; kx++)
                            v += xs[(ir + ky) * 68 + ic + kx] * sw1[c * 9 + ky * 3 + kx];
                    o[e] = (short)f2bf(fmaxf(fmaf(v, scr[e], shr[e]), 0.f));
                }
            } else {
#pragma unroll
                for (int e = 0; e < 8; e++) o[e] = 0;
            }
            int p = ic & 1;
            int psx = ir * 33 + (ic >> 1);
            *(short8*)(X + ((p * 198 + psx) << 6) + ((sub ^ (psx & 7)) << 3)) = o;
        }
    }
    __syncthreads();

    int l = w >> 1, oxb = (w & 1) * 16;
    int oxl = oxb + colL;
    f32x4 acc[4] = {};
    for (int kc = 0; kc < 32; ++kc) {
        int tap = kc >> 1;
        int ky = tap >> 2, kx = tap & 3;
        int chgrp = (kc & 1) * 4 + quad;
        int ir = 2 * l + ky;
        int p = kx & 1;
        int psx = ir * 33 + oxl + (kx >> 1);
        short8 bb = *(const short8*)(X + ((p * 198 + psx) << 6) + ((chgrp ^ (psx & 7)) << 3));
        const unsigned short* ap = Apk + (((kc << 6) + colL) << 5) + (quad << 3);
        short8 a0 = *(const short8*)(ap);
        short8 a1 = *(const short8*)(ap + 512);
        short8 a2 = *(const short8*)(ap + 1024);
        short8 a3 = *(const short8*)(ap + 1536);
        acc[0] = __builtin_amdgcn_mfma_f32_16x16x32_bf16(a0, bb, acc[0], 0, 0, 0);
        acc[1] = __builtin_amdgcn_mfma_f32_16x16x32_bf16(a1, bb, acc[1], 0, 0, 0);
        acc[2] = __builtin_amdgcn_mfma_f32_16x16x32_bf16(a2, bb, acc[2], 0, 0, 0);
        acc[3] = __builtin_amdgcn_mfma_f32_16x16x32_bf16(a3, bb, acc[3], 0, 0, 0);
    }

    float sl[16], s2l[16];
#pragma unroll
    for (int i = 0; i < 16; i++) { sl[i] = 0.f; s2l[i] = 0.f; }
    int oy = 2 * sy + l, oxg = xh * 32 + oxl;
#pragma unroll
    for (int mt = 0; mt < 4; ++mt) {
        int co0 = mt * 16 + quad * 4;
        size_t base = ((size_t)((b * 64 + oy) * 64 + oxg)) * 64 + co0;
        short4v o;
#pragma unroll
        for (int r = 0; r < 4; ++r) {
            unsigned short hh = f2bf(acc[mt][r] + sb2[co0 + r]);
            o[r] = (short)hh;
            float f = bf2f(hh);
            sl[mt * 4 + r] += f; s2l[mt * 4 + r] += f * f;
        }
        *(short4v*)(h2 + base) = o;
    }
#pragma unroll
    for (int idx = 0; idx < 16; ++idx) {
        float s = sl[idx], s2 = s2l[idx];
        s += __shfl_xor(s, 1, 64); s += __shfl_xor(s, 2, 64);
        s += __shfl_xor(s, 4, 64); s += __shfl_xor(s, 8, 64);
        s2 += __shfl_xor(s2, 1, 64); s2 += __shfl_xor(s2, 2, 64);
        s2 += __shfl_xor(s2, 4, 64); s2 += __shfl_xor(s2, 8, 64);
        if (colL == 0) {
            int co = (idx >> 2) * 16 + quad * 4 + (idx & 3);
            sred[w][co] = s; s2red[w][co] = s2;
        }
    }
    __syncthreads();
    if (tid < 64) {
        float s = sred[0][tid] + sred[1][tid] + sred[2][tid] + sred[3][tid];
        float s2 = s2red[0][tid] + s2red[1][tid] + s2red[2][tid] + s2red[3][tid];
        sums_out[(size_t)bx * 8192 + b * 64 + tid] = s;
        sums_out[(size_t)bx * 8192 + 4096 + b * 64 + tid] = s2;
    }
}

// ===== ds3mfma: h2(bf16 NHWC) -> GN2+ReLU on load -> conv4x4/s2 MFMA -> z,zb,zsums =====
__global__ __launch_bounds__(256) void ds3mfma_kernel(const unsigned short* __restrict__ h2,
    const float* __restrict__ sums_in, const float* __restrict__ gw, const float* __restrict__ gb,
    const unsigned short* __restrict__ Apk, const float* __restrict__ bias3,
    float* __restrict__ z, unsigned short* __restrict__ zb, float* __restrict__ sums_out) {
    __shared__ unsigned short X[2 * 198 * 64];
    __shared__ float ssc[64], ssh[64], sb3[64];
    __shared__ float sred[4][64], s2red[4][64];
    int tid = threadIdx.x;
    int b = blockIdx.y, sy = blockIdx.x;
    int lane = tid & 63, w = tid >> 6;
    int colL = lane & 15, quad = lane >> 4;

    if (tid < 64) {
        int c = tid;
        float s = 0.f, s2 = 0.f;
        const float* sp = sums_in + b * 64 + c;
        for (int i = 0; i < 64; i++) { s += sp[(size_t)i * 8192]; s2 += sp[(size_t)i * 8192 + 4096]; }
        float mean = s * (1.f / 4096.f);
        float var = fmaxf(s2 * (1.f / 4096.f) - mean * mean, 0.f);
        float sc = rsqrtf(var + 1e-5f) * gw[c];
        ssc[c] = sc;
        ssh[c] = gb[c] - mean * sc;
        sb3[c] = bias3[c];
    }
    __syncthreads();
    {
        int sub = tid & 7;
        float scr[8], shr[8];
#pragma unroll
        for (int e = 0; e < 8; e++) { scr[e] = ssc[sub * 8 + e]; shr[e] = ssh[sub * 8 + e]; }
        for (int i = tid; i < 3168; i += 256) {
            int pidx = i >> 3;
            int ir = pidx / 66, ic = pidx - ir * 66;
            int gy = 4 * sy - 1 + ir, gx = ic - 1;
            short8 o;
            if (gy >= 0 && gy < 64 && gx >= 0 && gx < 64) {
                short8 d = *(const short8*)(h2 + ((size_t)((b * 64 + gy) * 64 + gx)) * 64 + sub * 8);
#pragma unroll
                for (int e = 0; e < 8; e++) {
                    float f = bf2f((unsigned short)d[e]);
                    o[e] = (short)f2bf(fmaxf(fmaf(f, scr[e], shr[e]), 0.f));
                }
            } else {
#pragma unroll
                for (int e = 0; e < 8; e++) o[e] = 0;
            }
            int p = ic & 1;
            int psx = ir * 33 + (ic >> 1);
            *(short8*)(X + ((p * 198 + psx) << 6) + ((sub ^ (psx & 7)) << 3)) = o;
        }
    }
    __syncthreads();

    int l = w >> 1, oxb = (w & 1) * 16;
    int oxl = oxb + colL;
    f32x4 acc[4] = {};
    for (int kc = 0; kc < 32; ++kc) {
        int tap = kc >> 1;
        int ky = tap >> 2, kx = tap & 3;
        int chgrp = (kc & 1) * 4 + quad;
        int ir = 2 * l + ky;
        int p = kx & 1;
        int psx = ir * 33 + oxl + (kx >> 1);
        short8 bb = *(const short8*)(X + ((p * 198 + psx) << 6) + ((chgrp ^ (psx & 7)) << 3));
        const unsigned short* ap = Apk + (((kc << 6) + colL) << 5) + (quad << 3);
        short8 a0 = *(const short8*)(ap);
        short8 a1 = *(const short8*)(ap + 512);
        short8 a2 = *(const short8*)(ap + 1024);
        short8 a3 = *(const short8*)(ap + 1536);
        acc[0] = __builtin_amdgcn_mfma_f32_16x16x32_bf16(a0, bb, acc[0], 0, 0, 0);
        acc[1] = __builtin_amdgcn_mfma_f32_16x16x32_bf16(a1, bb, acc[1], 0, 0, 0);
        acc[2] = __builtin_amdgcn_mfma_f32_16x16x32_bf16(a2, bb, acc[2], 0, 0, 0);
        acc[3] = __builtin_amdgcn_mfma_f32_16x16x32_bf16(a3, bb, acc[3], 0, 0, 0);
    }

    float sl[16], s2l[16];
#pragma unroll
    for (int i = 0; i < 16; i++) { sl[i] = 0.f; s2l[i] = 0.f; }
    int py = 2 * sy + l;
#pragma unroll
    for (int mt = 0; mt < 4; ++mt) {
        int co0 = mt * 16 + quad * 4;
        size_t base = ((size_t)((b << 10) + py * 32 + oxl)) * 64 + co0;
        f32x4 zv;
        short4v o;
#pragma unroll
        for (int r = 0; r < 4; ++r) {
            float val = acc[mt][r] + sb3[co0 + r];
            zv[r] = val;
            unsigned short hh = f2bf(val);
            o[r] = (short)hh;
            float f = bf2f(hh);
            sl[mt * 4 + r] += f; s2l[mt * 4 + r] += f * f;
        }
        *(f32x4*)(z + base) = zv;
        *(short4v*)(zb + base) = o;
    }
#pragma unroll
    for (int idx = 0; idx < 16; ++idx) {
        float s = sl[idx], s2 = s2l[idx];
        s += __shfl_xor(s, 1, 64); s += __shfl_xor(s, 2, 64);
        s += __shfl_xor(s, 4, 64); s += __shfl_xor(s, 8, 64);
        s2 += __shfl_xor(s2, 1, 64); s2 += __shfl_xor(s2, 2, 64);
        s2 += __shfl_xor(s2, 4, 64); s2 += __shfl_xor(s2, 8, 64);
        if (colL == 0) {
            int co = (idx >> 2) * 16 + quad * 4 + (idx & 3);
            sred[w][co] = s; s2red[w][co] = s2;
        }
    }
    __syncthreads();
    if (tid < 64) {
        float s = sred[0][tid] + sred[1][tid] + sred[2][tid] + sred[3][tid];
        float s2 = s2red[0][tid] + s2red[1][tid] + s2red[2][tid] + s2red[3][tid];
        sums_out[(size_t)sy * 8192 + b * 64 + tid] = s;
        sums_out[(size_t)sy * 8192 + 4096 + b * 64 + tid] = s2;
    }
}

// ==================== MFMA implicit-GEMM ODE conv (3x3 pad1, 64+t -> 64) ============
// grid (64 samples, 4 strips): XCD-affinity mapping. A in LDS (APAD=40 pad: 2-way
// banks); staging + epilogue operands prefetched. kacc bf16; stats via sub-slots.
#define APAD 40
#define CONV_LDS_BYTES 142592
__global__ __launch_bounds__(512, 2) void convmfma_kernel(
    const unsigned short* __restrict__ uin, const float* __restrict__ sums_in, int nsub,
    const float* __restrict__ gw, const float* __restrict__ gb,
    const unsigned short* __restrict__ Apk, const float* __restrict__ stab,
    const float* __restrict__ bias, float t, float aa, int mode,
    float* __restrict__ z, const unsigned short* __restrict__ zbin,
    unsigned short* __restrict__ uout, unsigned short* __restrict__ kacc,
    float* __restrict__ sums_out)
{
    extern __shared__ unsigned short smem[];
    unsigned short* Aw = smem;                    // 18*64*APAD = 46080 shorts (92160 B)
    unsigned short* X  = smem + 46080;            // 21760 shorts (10*34*64)
    float* fp    = (float*)(smem + 67840);
    float* ssc   = fp;        float* ssh   = fp + 64;
    float* tS    = fp + 128;  float* trow0 = fp + 192;  float* trow2 = fp + 256;
    float* tcol0 = fp + 320;  float* tcol2 = fp + 384;
    float* tc00  = fp + 448;  float* tc02  = fp + 512;
    float* tc20  = fp + 576;  float* tc22  = fp + 640;
    float* sred  = fp + 704;             // [8][64]
    float* s2red = fp + 1216;            // [8][64]

    int tid = threadIdx.x;
    int b = blockIdx.x, strip = blockIdx.y;
    int y0 = strip * 8;
    int lane = tid & 63, w = tid >> 6;
    int colL = lane & 15, quad = lane >> 4;
    int sub = tid & 7;

    short8 dpre[5];
    int pr[5], pxc[5];
    bool pok[5];
#pragma unroll
    for (int it = 0; it < 5; ++it) {
        int pidx = (tid >> 3) + it * 64;
        int r = pidx >> 5, xc = pidx & 31;
        int gy = y0 - 1 + r;
        pr[it] = r; pxc[it] = xc;
        pok[it] = (gy >= 0 && gy <= 31);
        if (pok[it])
            dpre[it] = *(const short8*)(uin + ((size_t)((b << 10) + gy * 32 + xc)) * 64 + sub * 8);
    }

    {
        f32x4 zz = 0.f;
        for (int i = tid; i < 2720; i += 512) ((f32x4*)X)[i] = zz;
    }
    for (int i = tid; i < 4608; i += 512) {
        int row = i >> 2, part = i & 3;
        *(f32x4*)(Aw + row * APAD + part * 8) = ((const f32x4*)Apk)[i];
    }

    if (tid < 64) {
        int c = tid;
        float s = 0.f, s2 = 0.f;
        const float* sp = sums_in + b * 64 + c;
        for (int i = 0; i < nsub; i++) { s += sp[(size_t)i * 8192]; s2 += sp[(size_t)i * 8192 + 4096]; }
        float mean = s * (1.f / 1024.f);
        float var = fmaxf(s2 * (1.f / 1024.f) - mean * mean, 0.f);
        float sc = rsqrtf(var + 1e-5f) * gw[c];
        ssc[c] = sc;
        ssh[c] = gb[c] - mean * sc;
    } else if (tid < 128) {
        int co = tid - 64;
        float w0[9];
#pragma unroll
        for (int k = 0; k < 9; k++) w0[k] = stab[co * 9 + k] * t;
        tS[co] = bias[co] + w0[0]+w0[1]+w0[2]+w0[3]+w0[4]+w0[5]+w0[6]+w0[7]+w0[8];
        trow0[co] = w0[0] + w0[1] + w0[2];
        trow2[co] = w0[6] + w0[7] + w0[8];
        tcol0[co] = w0[0] + w0[3] + w0[6];
        tcol2[co] = w0[2] + w0[5] + w0[8];
        tc00[co] = w0[0]; tc02[co] = w0[2]; tc20[co] = w0[6]; tc22[co] = w0[8];
    }
    __syncthreads();

    {
        float scr[8], shr[8];
#pragma unroll
        for (int e = 0; e < 8; e++) { scr[e] = ssc[sub * 8 + e]; shr[e] = ssh[sub * 8 + e]; }
#pragma unroll
        for (int it = 0; it < 5; ++it) {
            if (!pok[it]) continue;
            short8 d = dpre[it];
            short8 o;
#pragma unroll
            for (int e = 0; e < 8; e++) {
                float f = bf2f((unsigned short)d[e]);
                o[e] = (short)f2bf(fmaxf(fmaf(f, scr[e], shr[e]), 0.f));
            }
            int psx = pr[it] * 34 + pxc[it] + 1;
            *(short8*)(X + (psx << 6) + ((sub ^ (psx & 7)) << 3)) = o;
        }
    }

    int py = y0 + w;
    short4v preZb[8], preK[8];
    f32x4 preZ[8];
    if (mode == 2) {
#pragma unroll
        for (int nt = 0; nt < 2; ++nt)
#pragma unroll
            for (int mt = 0; mt < 4; ++mt) {
                size_t base = ((size_t)((b << 10) + py * 32 + nt * 16 + colL)) * 64 + mt * 16 + quad * 4;
                preK[nt * 4 + mt] = *(const short4v*)(kacc + base);
                preZ[nt * 4 + mt] = *(const f32x4*)(z + base);
            }
    } else if (mode != 3) {
#pragma unroll
        for (int nt = 0; nt < 2; ++nt)
#pragma unroll
            for (int mt = 0; mt < 4; ++mt) {
                size_t base = ((size_t)((b << 10) + py * 32 + nt * 16 + colL)) * 64 + mt * 16 + quad * 4;
                preZb[nt * 4 + mt] = *(const short4v*)(zbin + base);
                if (mode == 1) preK[nt * 4 + mt] = *(const short4v*)(kacc + base);
            }
    }
    __syncthreads();

    f32x4 acc[4][2] = {};
    for (int kc = 0; kc < 18; ++kc) {
        int tap = kc >> 1;
        int dy = tap / 3, dx = tap % 3;
        int chgrp = (kc & 1) * 4 + quad;
        int ps0 = (w + dy) * 34 + colL + dx;
        int ps1 = ps0 + 16;
        short8 bb0 = *(const short8*)(X + (ps0 << 6) + ((chgrp ^ (ps0 & 7)) << 3));
        short8 bb1 = *(const short8*)(X + (ps1 << 6) + ((chgrp ^ (ps1 & 7)) << 3));
        const unsigned short* ap = Aw + ((kc << 6) + colL) * APAD + (quad << 3);
        short8 a0 = *(const short8*)(ap);
        short8 a1 = *(const short8*)(ap + 16 * APAD);
        short8 a2 = *(const short8*)(ap + 32 * APAD);
        short8 a3 = *(const short8*)(ap + 48 * APAD);
        acc[0][0] = __builtin_amdgcn_mfma_f32_16x16x32_bf16(a0, bb0, acc[0][0], 0, 0, 0);
        acc[0][1] = __builtin_amdgcn_mfma_f32_16x16x32_bf16(a0, bb1, acc[0][1], 0, 0, 0);
        acc[1][0] = __builtin_amdgcn_mfma_f32_16x16x32_bf16(a1, bb0, acc[1][0], 0, 0, 0);
        acc[1][1] = __builtin_amdgcn_mfma_f32_16x16x32_bf16(a1, bb1, acc[1][1], 0, 0, 0);
        acc[2][0] = __builtin_amdgcn_mfma_f32_16x16x32_bf16(a2, bb0, acc[2][0], 0, 0, 0);
        acc[2][1] = __builtin_amdgcn_mfma_f32_16x16x32_bf16(a2, bb1, acc[2][1], 0, 0, 0);
        acc[3][0] = __builtin_amdgcn_mfma_f32_16x16x32_bf16(a3, bb0, acc[3][0], 0, 0, 0);
        acc[3][1] = __builtin_amdgcn_mfma_f32_16x16x32_bf16(a3, bb1, acc[3][1], 0, 0, 0);
    }

    float sl[16], s2l[16];
#pragma unroll
    for (int i = 0; i < 16; i++) { sl[i] = 0.f; s2l[i] = 0.f; }
    bool by0 = (py == 0), by1 = (py == 31);
#pragma unroll
    for (int nt = 0; nt < 2; ++nt) {
        int px = nt * 16 + colL;
        bool bx0 = (px == 0), bx1 = (px == 31);
#pragma unroll
        for (int mt = 0; mt < 4; ++mt) {
            int co0 = mt * 16 + quad * 4;
            int pi = nt * 4 + mt;
            float vout[4];
#pragma unroll
            for (int r = 0; r < 4; ++r) {
                int co = co0 + r;
                float val = acc[mt][nt][r] + tS[co];
                if (by0) { val -= trow0[co]; if (bx0) val += tc00[co]; if (bx1) val += tc02[co]; }
                if (by1) { val -= trow2[co]; if (bx0) val += tc20[co]; if (bx1) val += tc22[co]; }
                if (bx0) val -= tcol0[co];
                if (bx1) val -= tcol2[co];
                vout[r] = val;
            }
            size_t base = ((size_t)((b << 10) + py * 32 + px)) * 64 + co0;
            if (mode == 3) {
                short4v o;
#pragma unroll
                for (int r = 0; r < 4; ++r) {
                    unsigned short hh = f2bf(vout[r]);
                    o[r] = (short)hh;
                    float f = bf2f(hh);
                    sl[mt * 4 + r] += f; s2l[mt * 4 + r] += f * f;
                }
                *(short4v*)(uout + base) = o;
            } else if (mode == 2) {
                f32x4 zv = preZ[pi];
                short4v kv = preK[pi];
                short4v o;
#pragma unroll
                for (int r = 0; r < 4; ++r) {
                    float zn = zv[r] + aa * (bf2f((unsigned short)kv[r]) + vout[r]);
                    zv[r] = zn;
                    unsigned short hh = f2bf(zn);
                    o[r] = (short)hh;
                    float f = bf2f(hh);
                    sl[mt * 4 + r] += f; s2l[mt * 4 + r] += f * f;
                }
                *(f32x4*)(z + base) = zv;
                *(short4v*)(uout + base) = o;
            } else {
                short4v zs = preZb[pi];
                short4v ko, o;
                if (mode == 1) {
                    short4v kv = preK[pi];
#pragma unroll
                    for (int r = 0; r < 4; ++r)
                        ko[r] = (short)f2bf(bf2f((unsigned short)kv[r]) + 2.f * vout[r]);
                } else {
#pragma unroll
                    for (int r = 0; r < 4; ++r) ko[r] = (short)f2bf(vout[r]);
                }
                *(short4v*)(kacc + base) = ko;
#pragma unroll
                for (int r = 0; r < 4; ++r) {
                    float zf = bf2f((unsigned short)zs[r]);
                    unsigned short hh = f2bf(zf + aa * vout[r]);
                    o[r] = (short)hh;
                    float f = bf2f(hh);
                    sl[mt * 4 + r] += f; s2l[mt * 4 + r] += f * f;
                }
                *(short4v*)(uout + base) = o;
            }
        }
    }
#pragma unroll
    for (int idx = 0; idx < 16; ++idx) {
        float s = sl[idx], s2 = s2l[idx];
        s += __shfl_xor(s, 1, 64); s += __shfl_xor(s, 2, 64);
        s += __shfl_xor(s, 4, 64); s += __shfl_xor(s, 8, 64);
        s2 += __shfl_xor(s2, 1, 64); s2 += __shfl_xor(s2, 2, 64);
        s2 += __shfl_xor(s2, 4, 64); s2 += __shfl_xor(s2, 8, 64);
        if (colL == 0) {
            int co = (idx >> 2) * 16 + quad * 4 + (idx & 3);
            sred[w * 64 + co] = s; s2red[w * 64 + co] = s2;
        }
    }
    __syncthreads();
    if (tid < 64) {
        float s = 0.f, s2 = 0.f;
#pragma unroll
        for (int i = 0; i < 8; i++) { s += sred[i * 64 + tid]; s2 += s2red[i * 64 + tid]; }
        sums_out[(size_t)strip * 8192 + b * 64 + tid] = s;
        sums_out[(size_t)strip * 8192 + 4096 + b * 64 + tid] = s2;
    }
}

// ================= head: GN + ReLU + GAP from NHWC z =================
__global__ __launch_bounds__(256) void headgap_kernel(const float* __restrict__ z,
    const float* __restrict__ w, const float* __restrict__ b, float* __restrict__ pooled) {
    __shared__ float r1[4][64], r2[4][64];
    __shared__ float scs[64], shs[64];
    int bq = blockIdx.x, tid = threadIdx.x;
    int c = tid & 63, g = tid >> 6;
    float s = 0.f, s2 = 0.f;
    for (int p = g; p < 1024; p += 4) {
        float v = z[((size_t)((bq << 10) + p)) * 64 + c];
        s += v; s2 += v * v;
    }
    r1[g][c] = s; r2[g][c] = s2;
    __syncthreads();
    if (tid < 64) {
        float ts = r1[0][tid] + r1[1][tid] + r1[2][tid] + r1[3][tid];
        float ts2 = r2[0][tid] + r2[1][tid] + r2[2][tid] + r2[3][tid];
        float mean = ts / 1024.f;
        float var = fmaxf(ts2 / 1024.f - mean * mean, 0.f);
        float sc = rsqrtf(var + 1e-5f) * w[tid];
        scs[tid] = sc;
        shs[tid] = b[tid] - mean * sc;
    }
    __syncthreads();
    float sc = scs[c], sh = shs[c];
    float r = 0.f;
    for (int p = g; p < 1024; p += 4)
        r += fmaxf(fmaf(z[((size_t)((bq << 10) + p)) * 64 + c], sc, sh), 0.f);
    r1[g][c] = r;
    __syncthreads();
    if (tid < 64)
        pooled[bq * 64 + tid] = (r1[0][tid] + r1[1][tid] + r1[2][tid] + r1[3][tid]) / 1024.f;
}

__global__ __launch_bounds__(256) void headfc_kernel(const float* __restrict__ pooled,
    const float* __restrict__ W, const float* __restrict__ bias, float* __restrict__ out) {
    int i = blockIdx.x * 256 + threadIdx.x;
    if (i < 640) {
        int b = i / 10, j = i % 10;
        float a = bias[j];
        const float* p = pooled + b * 64;
        const float* wj = W + j * 64;
#pragma unroll 8
        for (int c = 0; c < 64; c++) a += p[c] * wj[c];
        out[i] = a;
    }
}

extern "C" void kernel_launch(void* const* d_in, const int* in_sizes, int n_in,
                              void* d_out, int out_size, void* d_ws, size_t ws_size,
                              hipStream_t stream) {
    const float* x      = (const float*)d_in[0];
    const float* ds_w1  = (const float*)d_in[1];
    const float* ds_b1  = (const float*)d_in[2];
    const float* ds_n1w = (const float*)d_in[3];
    const float* ds_n1b = (const float*)d_in[4];
    const float* ds_w2  = (const float*)d_in[5];
    const float* ds_b2  = (const float*)d_in[6];
    const float* ds_n2w = (const float*)d_in[7];
    const float* ds_n2b = (const float*)d_in[8];
    const float* ds_w3  = (const float*)d_in[9];
    const float* ds_b3  = (const float*)d_in[10];
    const float* ode_w1 = (const float*)d_in[11];
    const float* ode_b1 = (const float*)d_in[12];
    const float* ode_n1w= (const float*)d_in[13];
    const float* ode_n1b= (const float*)d_in[14];
    const float* ode_w2 = (const float*)d_in[15];
    const float* ode_b2 = (const float*)d_in[16];
    const float* ode_n2w= (const float*)d_in[17];
    const float* ode_n2b= (const float*)d_in[18];
    const float* head_nw= (const float*)d_in[19];
    const float* head_nb= (const float*)d_in[20];
    const float* head_W = (const float*)d_in[21];
    const float* head_b = (const float*)d_in[22];

    const size_t NZ = (size_t)BB * CC * 32 * 32;   // 4,194,304
    float* ws = (float*)d_ws;
    float*          z     = ws;                                   // NZ fp32 NHWC
    unsigned short* zb    = (unsigned short*)(ws + NZ);           // NZ bf16
    unsigned short* u     = (unsigned short*)(ws + 3 * NZ / 2);   // NZ bf16
    unsigned short* v     = (unsigned short*)(ws + 2 * NZ);       // NZ bf16
    unsigned short* kacc  = (unsigned short*)(ws + 5 * NZ / 2);   // NZ bf16
    unsigned short* h2    = u;   // [B,64,64,64] NHWC bf16 spans [1.5NZ, 3.5NZ) fl, dead by ODE
    float*          apf   = ws + 7 * NZ / 2;
    unsigned short* Apk   = (unsigned short*)apf;                 // 204,800 shorts
    float*          Stab  = apf + 102400;                         // 1,152
    float*          ds2s  = Stab + 1152;                          // 64 sub * 8192
    float*          zsum  = ds2s + (size_t)64 * 8192;             // 16 sub * 8192
    float*          osl   = zsum + (size_t)16 * 8192;             // 80 slots * 4 sub * 8192
    float*          ps    = osl + (size_t)80 * 32768;             // 32,768
    float*          ps2   = ps + 32768;                           // 32,768
    float*          gn1sc = ps2 + 32768;                          // 4,096
    float*          gn1sh = gn1sc + 4096;                         // 4,096
    float*          pooled= gn1sh + 4096;                         // 4,096
    float*          endp  = pooled + 4096;
    // big-ws extension: h1n bf16 [B,128,128,64] = 67,108,864 shorts (33.55M floats)
    unsigned short* h1n   = (unsigned short*)endp;
    size_t need_bytes = ((size_t)(endp - ws) + (size_t)BB * 128 * 128 * 64 / 2) * sizeof(float);
    bool bigws = (ws_size >= need_bytes);

    auto OSL = [&](int j) { return osl + (size_t)j * 32768; };

    hipFuncSetAttribute(reinterpret_cast<const void*>(convmfma_kernel),
                        hipFuncAttributeMaxDynamicSharedMemorySize, CONV_LDS_BYTES);

    prepack_kernel<<<dim3(32, 4), 256, 0, stream>>>(ode_w1, ode_w2, ds_w2, ds_w3, Apk, Stab);

    // ---- downsampler ----
    conv1stats_kernel<<<dim3(8, BB), 256, 0, stream>>>(x, ds_w1, ds_b1, ps, ps2);
    gn1fin_kernel<<<16, 256, 0, stream>>>(ps, ps2, ds_n1w, ds_n1b, gn1sc, gn1sh);
    if (bigws) {
        ds1_kernel<<<dim3(32, BB), 256, 0, stream>>>(x, ds_w1, ds_b1, gn1sc, gn1sh, h1n);
        ds2b_kernel<<<dim3(64, BB), 256, 0, stream>>>(h1n, Apk + 73728, ds_b2, h2, ds2s);
    } else {
        ds2mfma_kernel<<<dim3(64, BB), 256, 0, stream>>>(x, ds_w1, ds_b1, gn1sc, gn1sh,
            Apk + 73728, ds_b2, h2, ds2s);
    }
    ds3mfma_kernel<<<dim3(16, BB), 256, 0, stream>>>(h2, ds2s, ds_n2w, ds_n2b,
        Apk + 139264, ds_b3, z, zb, zsum);

    // ---- ODE: 10 RK4 steps; grid (B, 4) for per-sample XCD affinity ----
    const unsigned short* AP1 = Apk;
    const unsigned short* AP2 = Apk + 36864;
    const float* ST1 = Stab;
    const float* ST2 = Stab + 576;
    const float c6 = 0.1f / 6.0f;
    dim3 cgrid(BB, 4);
    for (int i = 0; i < 10; i++) {
        float t0 = 0.1f * (float)i;
        int j = 8 * i;
        const float* s0 = (i == 0) ? zsum : OSL(j - 1);
        int n0 = (i == 0) ? 16 : 4;
        convmfma_kernel<<<cgrid, 512, CONV_LDS_BYTES, stream>>>(zb, s0, n0, ode_n1w, ode_n1b,
            AP1, ST1, ode_b1, t0, 0.f, 3, z, zb, v, kacc, OSL(j));
        convmfma_kernel<<<cgrid, 512, CONV_LDS_BYTES, stream>>>(v, OSL(j), 4, ode_n2w, ode_n2b,
            AP2, ST2, ode_b2, t0, 0.05f, 0, z, zb, u, kacc, OSL(j + 1));
        convmfma_kernel<<<cgrid, 512, CONV_LDS_BYTES, stream>>>(u, OSL(j + 1), 4, ode_n1w, ode_n1b,
            AP1, ST1, ode_b1, t0 + 0.05f, 0.f, 3, z, zb, v, kacc, OSL(j + 2));
        convmfma_kernel<<<cgrid, 512, CONV_LDS_BYTES, stream>>>(v, OSL(j + 2), 4, ode_n2w, ode_n2b,
            AP2, ST2, ode_b2, t0 + 0.05f, 0.05f, 1, z, zb, u, kacc, OSL(j + 3));
        convmfma_kernel<<<cgrid, 512, CONV_LDS_BYTES, stream>>>(u, OSL(j + 3), 4, ode_n1w, ode_n1b,
            AP1, ST1, ode_b1, t0 + 0.05f, 0.f, 3, z, zb, v, kacc, OSL(j + 4));
        convmfma_kernel<<<cgrid, 512, CONV_LDS_BYTES, stream>>>(v, OSL(j + 4), 4, ode_n2w, ode_n2b,
            AP2, ST2, ode_b2, t0 + 0.05f, 0.1f, 1, z, zb, u, kacc, OSL(j + 5));
        convmfma_kernel<<<cgrid, 512, CONV_LDS_BYTES, stream>>>(u, OSL(j + 5), 4, ode_n1w, ode_n1b,
            AP1, ST1, ode_b1, t0 + 0.1f, 0.f, 3, z, zb, v, kacc, OSL(j + 6));
        convmfma_kernel<<<cgrid, 512, CONV_LDS_BYTES, stream>>>(v, OSL(j + 6), 4, ode_n2w, ode_n2b,
            AP2, ST2, ode_b2, t0 + 0.1f, c6, 2, z, zb, zb, kacc, OSL(j + 7));
    }

    // ---- head ----
    headgap_kernel<<<BB, 256, 0, stream>>>(z, head_nw, head_nb, pooled);
    headfc_kernel<<<3, 256, 0, stream>>>(pooled, head_W, head_b, (float*)d_out);
}

// Round 14
// 2259.598 us; speedup vs baseline: 1.0960x; 1.0960x over previous
//
#include <hip/hip_runtime.h>

#define BB 64   // batch
#define CC 64   // channels

typedef __attribute__((ext_vector_type(8))) short short8;
typedef __attribute__((ext_vector_type(4))) short short4v;
typedef __attribute__((ext_vector_type(4))) float f32x4;

__device__ __forceinline__ float bf2f(unsigned short h) {
    unsigned int u = ((unsigned int)h) << 16;
    float f; __builtin_memcpy(&f, &u, 4); return f;
}
__device__ __forceinline__ unsigned short f2bf(float f) {
    unsigned int u; __builtin_memcpy(&u, &f, 4);
    u += 0x7fffu + ((u >> 16) & 1u);
    return (unsigned short)(u >> 16);
}

// ================= GN1 stats directly from x (recompute conv1) =================
__global__ __launch_bounds__(256) void conv1stats_kernel(const float* __restrict__ x,
    const float* __restrict__ w1, const float* __restrict__ b1,
    float* __restrict__ ps, float* __restrict__ ps2) {
    __shared__ float sw1[576];
    __shared__ float sb1[64];
    __shared__ float xs[10 * 130];
    int tid = threadIdx.x;
    int qq = blockIdx.x;
    int b = blockIdx.y;
    for (int i = tid; i < 576; i += 256) sw1[i] = w1[i];
    if (tid < 64) sb1[tid] = b1[tid];
    const float* xb = x + (size_t)b * 130 * 130;
    int c = tid >> 2, q = tid & 3;
    float s = 0.f, s2 = 0.f;
    for (int sidx = 0; sidx < 2; sidx++) {
        int row0 = (qq * 2 + sidx) * 8;
        __syncthreads();
        for (int i = tid; i < 1300; i += 256) xs[i] = xb[row0 * 130 + i];
        __syncthreads();
        const float* wc = &sw1[c * 9];
        float bc = sb1[c];
        for (int p = q; p < 1024; p += 4) {
            int y = p >> 7, xx = p & 127;
            float v = bc;
#pragma unroll
            for (int ky = 0; ky < 3; ky++)
#pragma unroll
                for (int kx = 0; kx < 3; kx++)
                    v += xs[(y + ky) * 130 + xx + kx] * wc[ky * 3 + kx];
            s += v; s2 += v * v;
        }
    }
    s  += __shfl_xor(s, 1, 64);  s  += __shfl_xor(s, 2, 64);
    s2 += __shfl_xor(s2, 1, 64); s2 += __shfl_xor(s2, 2, 64);
    if (q == 0) {
        ps [(b * 8 + qq) * 64 + c] = s;
        ps2[(b * 8 + qq) * 64 + c] = s2;
    }
}

__global__ __launch_bounds__(256) void gn1fin_kernel(const float* __restrict__ ps,
    const float* __restrict__ ps2, const float* __restrict__ n1w, const float* __restrict__ n1b,
    float* __restrict__ gn1sc, float* __restrict__ gn1sh) {
    int i = blockIdx.x * 256 + threadIdx.x;
    if (i >= BB * CC) return;
    int c = i & 63, b = i >> 6;
    float s = 0.f, s2 = 0.f;
#pragma unroll
    for (int qq = 0; qq < 8; qq++) {
        s  += ps [(b * 8 + qq) * 64 + c];
        s2 += ps2[(b * 8 + qq) * 64 + c];
    }
    float mean = s / 16384.f;
    float var = s2 / 16384.f - mean * mean;
    float rstd = rsqrtf(var + 1e-5f);
    float sc = rstd * n1w[c];
    gn1sc[i] = sc;
    gn1sh[i] = n1b[c] - mean * sc;
}

// ===== weight prepack, chunk-major A: Apk[kc][co][32] bf16 =====
__global__ __launch_bounds__(256) void prepack_kernel(const float* __restrict__ w1,
    const float* __restrict__ w2, const float* __restrict__ dw2,
    const float* __restrict__ dw3, unsigned short* __restrict__ Apk,
    float* __restrict__ Stab) {
    int set = blockIdx.y, kc = blockIdx.x, tid = threadIdx.x;
    int nchunk = (set < 2) ? 18 : 32;
    if (kc < nchunk) {
        const float* w = (set == 0) ? w1 : (set == 1) ? w2 : (set == 2) ? dw2 : dw3;
        size_t off = (set == 0) ? 0 : (set == 1) ? 36864 : (set == 2) ? 73728 : 139264;
        for (int e = tid; e < 2048; e += 256) {
            int co = e >> 5, j = e & 31;
            int k = kc * 32 + j;
            int ci = k & 63;
            int tap = k >> 6;
            float val;
            if (set < 2) val = w[(co * 65 + ci + 1) * 9 + tap];
            else         val = w[((co << 6) + ci) * 16 + tap];
            Apk[off + (size_t)kc * 2048 + e] = f2bf(val);
        }
    }
    if (set < 2 && kc == 0) {
        const float* w = set ? w2 : w1;
        for (int t = tid; t < 576; t += 256) {
            int co = t / 9, tap = t % 9;
            Stab[set * 576 + t] = w[(co * 65) * 9 + tap];
        }
    }
}

// ===== ds2mfma: x -> conv1 -> GN1 -> ReLU (in-register) -> conv4x4/s2 MFMA -> h2 =====
__global__ __launch_bounds__(256) void ds2mfma_kernel(const float* __restrict__ x,
    const float* __restrict__ w1, const float* __restrict__ b1,
    const float* __restrict__ gn1sc, const float* __restrict__ gn1sh,
    const unsigned short* __restrict__ Apk, const float* __restrict__ bias2,
    unsigned short* __restrict__ h2, float* __restrict__ sums_out) {
    __shared__ unsigned short X[2 * 198 * 64];
    __shared__ float xs[8 * 68];
    __shared__ float sw1[576];
    __shared__ float sb1[64], ssc[64], ssh[64], sb2[64];
    __shared__ float sred[4][64], s2red[4][64];
    int tid = threadIdx.x;
    int b = blockIdx.y;
    int bx = blockIdx.x;
    int xh = bx & 1, sy = bx >> 1;
    int lane = tid & 63, w = tid >> 6;
    int colL = lane & 15, quad = lane >> 4;

    for (int i = tid; i < 576; i += 256) sw1[i] = w1[i];
    if (tid < 64) {
        sb1[tid] = b1[tid];
        ssc[tid] = gn1sc[b * 64 + tid];
        ssh[tid] = gn1sh[b * 64 + tid];
        sb2[tid] = bias2[tid];
    }
    {
        const float* xb = x + (size_t)b * 130 * 130;
        for (int i = tid; i < 544; i += 256) {
            int r = i / 68, cc = i % 68;
            int xr = 4 * sy - 1 + r, xcg = 64 * xh - 1 + cc;
            xs[i] = (xr >= 0 && xr < 130 && xcg >= 0 && xcg < 130) ? xb[xr * 130 + xcg] : 0.f;
        }
    }
    __syncthreads();
    {
        int sub = tid & 7;
        float sbr[8], scr[8], shr[8];
#pragma unroll
        for (int e = 0; e < 8; e++) {
            int c = sub * 8 + e;
            sbr[e] = sb1[c]; scr[e] = ssc[c]; shr[e] = ssh[c];
        }
        for (int i = tid; i < 3168; i += 256) {
            int pidx = i >> 3;
            int ir = pidx / 66, ic = pidx - ir * 66;
            int gy = 4 * sy - 1 + ir, gxg = 64 * xh - 1 + ic;
            short8 o;
            if (gy >= 0 && gy < 128 && gxg >= 0 && gxg < 128) {
#pragma unroll
                for (int e = 0; e < 8; e++) {
                    int c = sub * 8 + e;
                    float v = sbr[e];
#pragma unroll
                    for (int ky = 0; ky < 3; ky++)
#pragma unroll
                        for (int kx = 0; kx < 3; kx++)
                            v += xs[(ir + ky) * 68 + ic + kx] * sw1[c * 9 + ky * 3 + kx];
                    o[e] = (short)f2bf(fmaxf(fmaf(v, scr[e], shr[e]), 0.f));
                }
            } else {
#pragma unroll
                for (int e = 0; e < 8; e++) o[e] = 0;
            }
            int p = ic & 1;
            int psx = ir * 33 + (ic >> 1);
            *(short8*)(X + ((p * 198 + psx) << 6) + ((sub ^ (psx & 7)) << 3)) = o;
        }
    }
    __syncthreads();

    int l = w >> 1, oxb = (w & 1) * 16;
    int oxl = oxb + colL;
    f32x4 acc[4] = {};
    for (int kc = 0; kc < 32; ++kc) {
        int tap = kc >> 1;
        int ky = tap >> 2, kx = tap & 3;
        int chgrp = (kc & 1) * 4 + quad;
        int ir = 2 * l + ky;
        int p = kx & 1;
        int psx = ir * 33 + oxl + (kx >> 1);
        short8 bb = *(const short8*)(X + ((p * 198 + psx) << 6) + ((chgrp ^ (psx & 7)) << 3));
        const unsigned short* ap = Apk + (((kc << 6) + colL) << 5) + (quad << 3);
        short8 a0 = *(const short8*)(ap);
        short8 a1 = *(const short8*)(ap + 512);
        short8 a2 = *(const short8*)(ap + 1024);
        short8 a3 = *(const short8*)(ap + 1536);
        acc[0] = __builtin_amdgcn_mfma_f32_16x16x32_bf16(a0, bb, acc[0], 0, 0, 0);
        acc[1] = __builtin_amdgcn_mfma_f32_16x16x32_bf16(a1, bb, acc[1], 0, 0, 0);
        acc[2] = __builtin_amdgcn_mfma_f32_16x16x32_bf16(a2, bb, acc[2], 0, 0, 0);
        acc[3] = __builtin_amdgcn_mfma_f32_16x16x32_bf16(a3, bb, acc[3], 0, 0, 0);
    }

    float sl[16], s2l[16];
#pragma unroll
    for (int i = 0; i < 16; i++) { sl[i] = 0.f; s2l[i] = 0.f; }
    int oy = 2 * sy + l, oxg = xh * 32 + oxl;
#pragma unroll
    for (int mt = 0; mt < 4; ++mt) {
        int co0 = mt * 16 + quad * 4;
        size_t base = ((size_t)((b * 64 + oy) * 64 + oxg)) * 64 + co0;
        short4v o;
#pragma unroll
        for (int r = 0; r < 4; ++r) {
            unsigned short hh = f2bf(acc[mt][r] + sb2[co0 + r]);
            o[r] = (short)hh;
            float f = bf2f(hh);
            sl[mt * 4 + r] += f; s2l[mt * 4 + r] += f * f;
        }
        *(short4v*)(h2 + base) = o;
    }
#pragma unroll
    for (int idx = 0; idx < 16; ++idx) {
        float s = sl[idx], s2 = s2l[idx];
        s += __shfl_xor(s, 1, 64); s += __shfl_xor(s, 2, 64);
        s += __shfl_xor(s, 4, 64); s += __shfl_xor(s, 8, 64);
        s2 += __shfl_xor(s2, 1, 64); s2 += __shfl_xor(s2, 2, 64);
        s2 += __shfl_xor(s2, 4, 64); s2 += __shfl_xor(s2, 8, 64);
        if (colL == 0) {
            int co = (idx >> 2) * 16 + quad * 4 + (idx & 3);
            sred[w][co] = s; s2red[w][co] = s2;
        }
    }
    __syncthreads();
    if (tid < 64) {
        float s = sred[0][tid] + sred[1][tid] + sred[2][tid] + sred[3][tid];
        float s2 = s2red[0][tid] + s2red[1][tid] + s2red[2][tid] + s2red[3][tid];
        sums_out[(size_t)bx * 8192 + b * 64 + tid] = s;
        sums_out[(size_t)bx * 8192 + 4096 + b * 64 + tid] = s2;
    }
}

// ===== ds3mfma: h2(bf16 NHWC) -> GN2+ReLU on load -> conv4x4/s2 MFMA -> z,zb,zsums =====
__global__ __launch_bounds__(256) void ds3mfma_kernel(const unsigned short* __restrict__ h2,
    const float* __restrict__ sums_in, const float* __restrict__ gw, const float* __restrict__ gb,
    const unsigned short* __restrict__ Apk, const float* __restrict__ bias3,
    float* __restrict__ z, unsigned short* __restrict__ zb, float* __restrict__ sums_out) {
    __shared__ unsigned short X[2 * 198 * 64];
    __shared__ float ssc[64], ssh[64], sb3[64];
    __shared__ float sred[4][64], s2red[4][64];
    int tid = threadIdx.x;
    int b = blockIdx.y, sy = blockIdx.x;
    int lane = tid & 63, w = tid >> 6;
    int colL = lane & 15, quad = lane >> 4;

    if (tid < 64) {
        int c = tid;
        float s = 0.f, s2 = 0.f;
        const float* sp = sums_in + b * 64 + c;
        for (int i = 0; i < 64; i++) { s += sp[(size_t)i * 8192]; s2 += sp[(size_t)i * 8192 + 4096]; }
        float mean = s * (1.f / 4096.f);
        float var = fmaxf(s2 * (1.f / 4096.f) - mean * mean, 0.f);
        float sc = rsqrtf(var + 1e-5f) * gw[c];
        ssc[c] = sc;
        ssh[c] = gb[c] - mean * sc;
        sb3[c] = bias3[c];
    }
    __syncthreads();
    {
        int sub = tid & 7;
        float scr[8], shr[8];
#pragma unroll
        for (int e = 0; e < 8; e++) { scr[e] = ssc[sub * 8 + e]; shr[e] = ssh[sub * 8 + e]; }
        for (int i = tid; i < 3168; i += 256) {
            int pidx = i >> 3;
            int ir = pidx / 66, ic = pidx - ir * 66;
            int gy = 4 * sy - 1 + ir, gx = ic - 1;
            short8 o;
            if (gy >= 0 && gy < 64 && gx >= 0 && gx < 64) {
                short8 d = *(const short8*)(h2 + ((size_t)((b * 64 + gy) * 64 + gx)) * 64 + sub * 8);
#pragma unroll
                for (int e = 0; e < 8; e++) {
                    float f = bf2f((unsigned short)d[e]);
                    o[e] = (short)f2bf(fmaxf(fmaf(f, scr[e], shr[e]), 0.f));
                }
            } else {
#pragma unroll
                for (int e = 0; e < 8; e++) o[e] = 0;
            }
            int p = ic & 1;
            int psx = ir * 33 + (ic >> 1);
            *(short8*)(X + ((p * 198 + psx) << 6) + ((sub ^ (psx & 7)) << 3)) = o;
        }
    }
    __syncthreads();

    int l = w >> 1, oxb = (w & 1) * 16;
    int oxl = oxb + colL;
    f32x4 acc[4] = {};
    for (int kc = 0; kc < 32; ++kc) {
        int tap = kc >> 1;
        int ky = tap >> 2, kx = tap & 3;
        int chgrp = (kc & 1) * 4 + quad;
        int ir = 2 * l + ky;
        int p = kx & 1;
        int psx = ir * 33 + oxl + (kx >> 1);
        short8 bb = *(const short8*)(X + ((p * 198 + psx) << 6) + ((chgrp ^ (psx & 7)) << 3));
        const unsigned short* ap = Apk + (((kc << 6) + colL) << 5) + (quad << 3);
        short8 a0 = *(const short8*)(ap);
        short8 a1 = *(const short8*)(ap + 512);
        short8 a2 = *(const short8*)(ap + 1024);
        short8 a3 = *(const short8*)(ap + 1536);
        acc[0] = __builtin_amdgcn_mfma_f32_16x16x32_bf16(a0, bb, acc[0], 0, 0, 0);
        acc[1] = __builtin_amdgcn_mfma_f32_16x16x32_bf16(a1, bb, acc[1], 0, 0, 0);
        acc[2] = __builtin_amdgcn_mfma_f32_16x16x32_bf16(a2, bb, acc[2], 0, 0, 0);
        acc[3] = __builtin_amdgcn_mfma_f32_16x16x32_bf16(a3, bb, acc[3], 0, 0, 0);
    }

    float sl[16], s2l[16];
#pragma unroll
    for (int i = 0; i < 16; i++) { sl[i] = 0.f; s2l[i] = 0.f; }
    int py = 2 * sy + l;
#pragma unroll
    for (int mt = 0; mt < 4; ++mt) {
        int co0 = mt * 16 + quad * 4;
        size_t base = ((size_t)((b << 10) + py * 32 + oxl)) * 64 + co0;
        f32x4 zv;
        short4v o;
#pragma unroll
        for (int r = 0; r < 4; ++r) {
            float val = acc[mt][r] + sb3[co0 + r];
            zv[r] = val;
            unsigned short hh = f2bf(val);
            o[r] = (short)hh;
            float f = bf2f(hh);
            sl[mt * 4 + r] += f; s2l[mt * 4 + r] += f * f;
        }
        *(f32x4*)(z + base) = zv;
        *(short4v*)(zb + base) = o;
    }
#pragma unroll
    for (int idx = 0; idx < 16; ++idx) {
        float s = sl[idx], s2 = s2l[idx];
        s += __shfl_xor(s, 1, 64); s += __shfl_xor(s, 2, 64);
        s += __shfl_xor(s, 4, 64); s += __shfl_xor(s, 8, 64);
        s2 += __shfl_xor(s2, 1, 64); s2 += __shfl_xor(s2, 2, 64);
        s2 += __shfl_xor(s2, 4, 64); s2 += __shfl_xor(s2, 8, 64);
        if (colL == 0) {
            int co = (idx >> 2) * 16 + quad * 4 + (idx & 3);
            sred[w][co] = s; s2red[w][co] = s2;
        }
    }
    __syncthreads();
    if (tid < 64) {
        float s = sred[0][tid] + sred[1][tid] + sred[2][tid] + sred[3][tid];
        float s2 = s2red[0][tid] + s2red[1][tid] + s2red[2][tid] + s2red[3][tid];
        sums_out[(size_t)sy * 8192 + b * 64 + tid] = s;
        sums_out[(size_t)sy * 8192 + 4096 + b * 64 + tid] = s2;
    }
}

// ==================== MFMA implicit-GEMM ODE conv (3x3 pad1, 64+t -> 64) ============
// grid (64 samples, 4 strips): XCD-affinity. A in LDS (APAD=40). Epilogue outputs
// staged through LDS (X reused) -> cooperative full-line coalesced global stores
// (block's uout/kacc regions are 32 KB contiguous each).
#define APAD 40
#define CONV_LDS_BYTES 142592
__global__ __launch_bounds__(512, 2) void convmfma_kernel(
    const unsigned short* __restrict__ uin, const float* __restrict__ sums_in, int nsub,
    const float* __restrict__ gw, const float* __restrict__ gb,
    const unsigned short* __restrict__ Apk, const float* __restrict__ stab,
    const float* __restrict__ bias, float t, float aa, int mode,
    float* __restrict__ z, const unsigned short* __restrict__ zbin,
    unsigned short* __restrict__ uout, unsigned short* __restrict__ kacc,
    float* __restrict__ sums_out)
{
    extern __shared__ unsigned short smem[];
    unsigned short* Aw = smem;                    // 46080 shorts (92160 B)
    unsigned short* X  = smem + 46080;            // 21760 shorts (10*34*64)
    float* fp    = (float*)(smem + 67840);
    float* ssc   = fp;        float* ssh   = fp + 64;
    float* tS    = fp + 128;  float* trow0 = fp + 192;  float* trow2 = fp + 256;
    float* tcol0 = fp + 320;  float* tcol2 = fp + 384;
    float* tc00  = fp + 448;  float* tc02  = fp + 512;
    float* tc20  = fp + 576;  float* tc22  = fp + 640;
    float* sred  = fp + 704;             // [8][64]
    float* s2red = fp + 1216;            // [8][64]

    int tid = threadIdx.x;
    int b = blockIdx.x, strip = blockIdx.y;
    int y0 = strip * 8;
    int lane = tid & 63, w = tid >> 6;
    int colL = lane & 15, quad = lane >> 4;
    int sub = tid & 7;

    short8 dpre[5];
    int pr[5], pxc[5];
    bool pok[5];
#pragma unroll
    for (int it = 0; it < 5; ++it) {
        int pidx = (tid >> 3) + it * 64;
        int r = pidx >> 5, xc = pidx & 31;
        int gy = y0 - 1 + r;
        pr[it] = r; pxc[it] = xc;
        pok[it] = (gy >= 0 && gy <= 31);
        if (pok[it])
            dpre[it] = *(const short8*)(uin + ((size_t)((b << 10) + gy * 32 + xc)) * 64 + sub * 8);
    }

    {
        f32x4 zz = 0.f;
        for (int i = tid; i < 2720; i += 512) ((f32x4*)X)[i] = zz;
    }
    for (int i = tid; i < 4608; i += 512) {
        int row = i >> 2, part = i & 3;
        *(f32x4*)(Aw + row * APAD + part * 8) = ((const f32x4*)Apk)[i];
    }

    if (tid < 64) {
        int c = tid;
        float s = 0.f, s2 = 0.f;
        const float* sp = sums_in + b * 64 + c;
        for (int i = 0; i < nsub; i++) { s += sp[(size_t)i * 8192]; s2 += sp[(size_t)i * 8192 + 4096]; }
        float mean = s * (1.f / 1024.f);
        float var = fmaxf(s2 * (1.f / 1024.f) - mean * mean, 0.f);
        float sc = rsqrtf(var + 1e-5f) * gw[c];
        ssc[c] = sc;
        ssh[c] = gb[c] - mean * sc;
    } else if (tid < 128) {
        int co = tid - 64;
        float w0[9];
#pragma unroll
        for (int k = 0; k < 9; k++) w0[k] = stab[co * 9 + k] * t;
        tS[co] = bias[co] + w0[0]+w0[1]+w0[2]+w0[3]+w0[4]+w0[5]+w0[6]+w0[7]+w0[8];
        trow0[co] = w0[0] + w0[1] + w0[2];
        trow2[co] = w0[6] + w0[7] + w0[8];
        tcol0[co] = w0[0] + w0[3] + w0[6];
        tcol2[co] = w0[2] + w0[5] + w0[8];
        tc00[co] = w0[0]; tc02[co] = w0[2]; tc20[co] = w0[6]; tc22[co] = w0[8];
    }
    __syncthreads();

    {
        float scr[8], shr[8];
#pragma unroll
        for (int e = 0; e < 8; e++) { scr[e] = ssc[sub * 8 + e]; shr[e] = ssh[sub * 8 + e]; }
#pragma unroll
        for (int it = 0; it < 5; ++it) {
            if (!pok[it]) continue;
            short8 d = dpre[it];
            short8 o;
#pragma unroll
            for (int e = 0; e < 8; e++) {
                float f = bf2f((unsigned short)d[e]);
                o[e] = (short)f2bf(fmaxf(fmaf(f, scr[e], shr[e]), 0.f));
            }
            int psx = pr[it] * 34 + pxc[it] + 1;
            *(short8*)(X + (psx << 6) + ((sub ^ (psx & 7)) << 3)) = o;
        }
    }

    int py = y0 + w;
    short4v preZb[8], preK[8];
    f32x4 preZ[8];
    if (mode == 2) {
#pragma unroll
        for (int nt = 0; nt < 2; ++nt)
#pragma unroll
            for (int mt = 0; mt < 4; ++mt) {
                size_t base = ((size_t)((b << 10) + py * 32 + nt * 16 + colL)) * 64 + mt * 16 + quad * 4;
                preK[nt * 4 + mt] = *(const short4v*)(kacc + base);
                preZ[nt * 4 + mt] = *(const f32x4*)(z + base);
            }
    } else if (mode != 3) {
#pragma unroll
        for (int nt = 0; nt < 2; ++nt)
#pragma unroll
            for (int mt = 0; mt < 4; ++mt) {
                size_t base = ((size_t)((b << 10) + py * 32 + nt * 16 + colL)) * 64 + mt * 16 + quad * 4;
                preZb[nt * 4 + mt] = *(const short4v*)(zbin + base);
                if (mode == 1) preK[nt * 4 + mt] = *(const short4v*)(kacc + base);
            }
    }
    __syncthreads();

    f32x4 acc[4][2] = {};
    for (int kc = 0; kc < 18; ++kc) {
        int tap = kc >> 1;
        int dy = tap / 3, dx = tap % 3;
        int chgrp = (kc & 1) * 4 + quad;
        int ps0 = (w + dy) * 34 + colL + dx;
        int ps1 = ps0 + 16;
        short8 bb0 = *(const short8*)(X + (ps0 << 6) + ((chgrp ^ (ps0 & 7)) << 3));
        short8 bb1 = *(const short8*)(X + (ps1 << 6) + ((chgrp ^ (ps1 & 7)) << 3));
        const unsigned short* ap = Aw + ((kc << 6) + colL) * APAD + (quad << 3);
        short8 a0 = *(const short8*)(ap);
        short8 a1 = *(const short8*)(ap + 16 * APAD);
        short8 a2 = *(const short8*)(ap + 32 * APAD);
        short8 a3 = *(const short8*)(ap + 48 * APAD);
        acc[0][0] = __builtin_amdgcn_mfma_f32_16x16x32_bf16(a0, bb0, acc[0][0], 0, 0, 0);
        acc[0][1] = __builtin_amdgcn_mfma_f32_16x16x32_bf16(a0, bb1, acc[0][1], 0, 0, 0);
        acc[1][0] = __builtin_amdgcn_mfma_f32_16x16x32_bf16(a1, bb0, acc[1][0], 0, 0, 0);
        acc[1][1] = __builtin_amdgcn_mfma_f32_16x16x32_bf16(a1, bb1, acc[1][1], 0, 0, 0);
        acc[2][0] = __builtin_amdgcn_mfma_f32_16x16x32_bf16(a2, bb0, acc[2][0], 0, 0, 0);
        acc[2][1] = __builtin_amdgcn_mfma_f32_16x16x32_bf16(a2, bb1, acc[2][1], 0, 0, 0);
        acc[3][0] = __builtin_amdgcn_mfma_f32_16x16x32_bf16(a3, bb0, acc[3][0], 0, 0, 0);
        acc[3][1] = __builtin_amdgcn_mfma_f32_16x16x32_bf16(a3, bb1, acc[3][1], 0, 0, 0);
    }

    // epilogue compute: pieces into registers; z (mode 2) stored direct (fp32)
    float sl[16], s2l[16];
#pragma unroll
    for (int i = 0; i < 16; i++) { sl[i] = 0.f; s2l[i] = 0.f; }
    bool by0 = (py == 0), by1 = (py == 31);
    short4v oPc[8], kPc[8];
#pragma unroll
    for (int nt = 0; nt < 2; ++nt) {
        int px = nt * 16 + colL;
        bool bx0 = (px == 0), bx1 = (px == 31);
#pragma unroll
        for (int mt = 0; mt < 4; ++mt) {
            int co0 = mt * 16 + quad * 4;
            int pi = nt * 4 + mt;
            float vout[4];
#pragma unroll
            for (int r = 0; r < 4; ++r) {
                int co = co0 + r;
                float val = acc[mt][nt][r] + tS[co];
                if (by0) { val -= trow0[co]; if (bx0) val += tc00[co]; if (bx1) val += tc02[co]; }
                if (by1) { val -= trow2[co]; if (bx0) val += tc20[co]; if (bx1) val += tc22[co]; }
                if (bx0) val -= tcol0[co];
                if (bx1) val -= tcol2[co];
                vout[r] = val;
            }
            if (mode == 3) {
#pragma unroll
                for (int r = 0; r < 4; ++r) {
                    unsigned short hh = f2bf(vout[r]);
                    oPc[pi][r] = (short)hh;
                    float f = bf2f(hh);
                    sl[mt * 4 + r] += f; s2l[mt * 4 + r] += f * f;
                }
            } else if (mode == 2) {
                f32x4 zv = preZ[pi];
                short4v kv = preK[pi];
#pragma unroll
                for (int r = 0; r < 4; ++r) {
                    float zn = zv[r] + aa * (bf2f((unsigned short)kv[r]) + vout[r]);
                    zv[r] = zn;
                    unsigned short hh = f2bf(zn);
                    oPc[pi][r] = (short)hh;
                    float f = bf2f(hh);
                    sl[mt * 4 + r] += f; s2l[mt * 4 + r] += f * f;
                }
                size_t base = ((size_t)((b << 10) + py * 32 + px)) * 64 + co0;
                *(f32x4*)(z + base) = zv;
            } else {
                short4v zs = preZb[pi];
                if (mode == 1) {
                    short4v kv = preK[pi];
#pragma unroll
                    for (int r = 0; r < 4; ++r)
                        kPc[pi][r] = (short)f2bf(bf2f((unsigned short)kv[r]) + 2.f * vout[r]);
                } else {
#pragma unroll
                    for (int r = 0; r < 4; ++r) kPc[pi][r] = (short)f2bf(vout[r]);
                }
#pragma unroll
                for (int r = 0; r < 4; ++r) {
                    float zf = bf2f((unsigned short)zs[r]);
                    unsigned short hh = f2bf(zf + aa * vout[r]);
                    oPc[pi][r] = (short)hh;
                    float f = bf2f(hh);
                    sl[mt * 4 + r] += f; s2l[mt * 4 + r] += f * f;
                }
            }
        }
    }

    // ---- staged coalesced stores: block's region = 256 px x 64 ch contiguous ----
    unsigned short* S1 = X;                      // X free after K-loop
    size_t gbase = ((size_t)((b << 10) + y0 * 32)) << 6;   // shorts
    __syncthreads();                             // all K-loop X reads done
#pragma unroll
    for (int pi = 0; pi < 8; ++pi) {
        int nt = pi >> 2, mt = pi & 3;
        int px = nt * 16 + colL, co0 = mt * 16 + quad * 4;
        int g = co0 >> 3, off = co0 & 7;
        *(short4v*)(S1 + (((w << 5) + px) << 6) + ((g ^ (px & 7)) << 3) + off) = oPc[pi];
    }
    __syncthreads();
#pragma unroll
    for (int it2 = 0; it2 < 4; ++it2) {
        int i = tid + it2 * 512;
        int p = i >> 3, j = i & 7;
        short8 d = *(short8*)(S1 + (p << 6) + ((j ^ (p & 7)) << 3));
        *(short8*)(uout + gbase + (size_t)i * 8) = d;
    }
    if (mode == 0 || mode == 1) {
        __syncthreads();
#pragma unroll
        for (int pi = 0; pi < 8; ++pi) {
            int nt = pi >> 2, mt = pi & 3;
            int px = nt * 16 + colL, co0 = mt * 16 + quad * 4;
            int g = co0 >> 3, off = co0 & 7;
            *(short4v*)(S1 + (((w << 5) + px) << 6) + ((g ^ (px & 7)) << 3) + off) = kPc[pi];
        }
        __syncthreads();
#pragma unroll
        for (int it2 = 0; it2 < 4; ++it2) {
            int i = tid + it2 * 512;
            int p = i >> 3, j = i & 7;
            short8 d = *(short8*)(S1 + (p << 6) + ((j ^ (p & 7)) << 3));
            *(short8*)(kacc + gbase + (size_t)i * 8) = d;
        }
    }

#pragma unroll
    for (int idx = 0; idx < 16; ++idx) {
        float s = sl[idx], s2 = s2l[idx];
        s += __shfl_xor(s, 1, 64); s += __shfl_xor(s, 2, 64);
        s += __shfl_xor(s, 4, 64); s += __shfl_xor(s, 8, 64);
        s2 += __shfl_xor(s2, 1, 64); s2 += __shfl_xor(s2, 2, 64);
        s2 += __shfl_xor(s2, 4, 64); s2 += __shfl_xor(s2, 8, 64);
        if (colL == 0) {
            int co = (idx >> 2) * 16 + quad * 4 + (idx & 3);
            sred[w * 64 + co] = s; s2red[w * 64 + co] = s2;
        }
    }
    __syncthreads();
    if (tid < 64) {
        float s = 0.f, s2 = 0.f;
#pragma unroll
        for (int i = 0; i < 8; i++) { s += sred[i * 64 + tid]; s2 += s2red[i * 64 + tid]; }
        sums_out[(size_t)strip * 8192 + b * 64 + tid] = s;
        sums_out[(size_t)strip * 8192 + 4096 + b * 64 + tid] = s2;
    }
}

// ================= head: GN + ReLU + GAP from NHWC z =================
__global__ __launch_bounds__(256) void headgap_kernel(const float* __restrict__ z,
    const float* __restrict__ w, const float* __restrict__ b, float* __restrict__ pooled) {
    __shared__ float r1[4][64], r2[4][64];
    __shared__ float scs[64], shs[64];
    int bq = blockIdx.x, tid = threadIdx.x;
    int c = tid & 63, g = tid >> 6;
    float s = 0.f, s2 = 0.f;
    for (int p = g; p < 1024; p += 4) {
        float v = z[((size_t)((bq << 10) + p)) * 64 + c];
        s += v; s2 += v * v;
    }
    r1[g][c] = s; r2[g][c] = s2;
    __syncthreads();
    if (tid < 64) {
        float ts = r1[0][tid] + r1[1][tid] + r1[2][tid] + r1[3][tid];
        float ts2 = r2[0][tid] + r2[1][tid] + r2[2][tid] + r2[3][tid];
        float mean = ts / 1024.f;
        float var = fmaxf(ts2 / 1024.f - mean * mean, 0.f);
        float sc = rsqrtf(var + 1e-5f) * w[tid];
        scs[tid] = sc;
        shs[tid] = b[tid] - mean * sc;
    }
    __syncthreads();
    float sc = scs[c], sh = shs[c];
    float r = 0.f;
    for (int p = g; p < 1024; p += 4)
        r += fmaxf(fmaf(z[((size_t)((bq << 10) + p)) * 64 + c], sc, sh), 0.f);
    r1[g][c] = r;
    __syncthreads();
    if (tid < 64)
        pooled[bq * 64 + tid] = (r1[0][tid] + r1[1][tid] + r1[2][tid] + r1[3][tid]) / 1024.f;
}

__global__ __launch_bounds__(256) void headfc_kernel(const float* __restrict__ pooled,
    const float* __restrict__ W, const float* __restrict__ bias, float* __restrict__ out) {
    int i = blockIdx.x * 256 + threadIdx.x;
    if (i < 640) {
        int b = i / 10, j = i % 10;
        float a = bias[j];
        const float* p = pooled + b * 64;
        const float* wj = W + j * 64;
#pragma unroll 8
        for (int c = 0; c < 64; c++) a += p[c] * wj[c];
        out[i] = a;
    }
}

extern "C" void kernel_launch(void* const* d_in, const int* in_sizes, int n_in,
                              void* d_out, int out_size, void* d_ws, size_t ws_size,
                              hipStream_t stream) {
    const float* x      = (const float*)d_in[0];
    const float* ds_w1  = (const float*)d_in[1];
    const float* ds_b1  = (const float*)d_in[2];
    const float* ds_n1w = (const float*)d_in[3];
    const float* ds_n1b = (const float*)d_in[4];
    const float* ds_w2  = (const float*)d_in[5];
    const float* ds_b2  = (const float*)d_in[6];
    const float* ds_n2w = (const float*)d_in[7];
    const float* ds_n2b = (const float*)d_in[8];
    const float* ds_w3  = (const float*)d_in[9];
    const float* ds_b3  = (const float*)d_in[10];
    const float* ode_w1 = (const float*)d_in[11];
    const float* ode_b1 = (const float*)d_in[12];
    const float* ode_n1w= (const float*)d_in[13];
    const float* ode_n1b= (const float*)d_in[14];
    const float* ode_w2 = (const float*)d_in[15];
    const float* ode_b2 = (const float*)d_in[16];
    const float* ode_n2w= (const float*)d_in[17];
    const float* ode_n2b= (const float*)d_in[18];
    const float* head_nw= (const float*)d_in[19];
    const float* head_nb= (const float*)d_in[20];
    const float* head_W = (const float*)d_in[21];
    const float* head_b = (const float*)d_in[22];

    const size_t NZ = (size_t)BB * CC * 32 * 32;   // 4,194,304
    float* ws = (float*)d_ws;
    float*          z     = ws;                                   // NZ fp32 NHWC
    unsigned short* zb    = (unsigned short*)(ws + NZ);           // NZ bf16
    unsigned short* u     = (unsigned short*)(ws + 3 * NZ / 2);   // NZ bf16
    unsigned short* v     = (unsigned short*)(ws + 2 * NZ);       // NZ bf16
    unsigned short* kacc  = (unsigned short*)(ws + 5 * NZ / 2);   // NZ bf16
    unsigned short* h2    = u;   // [B,64,64,64] NHWC bf16 spans [1.5NZ, 3.5NZ) fl, dead by ODE
    float*          apf   = ws + 7 * NZ / 2;
    unsigned short* Apk   = (unsigned short*)apf;                 // 204,800 shorts
    float*          Stab  = apf + 102400;                         // 1,152
    float*          ds2s  = Stab + 1152;                          // 64 sub * 8192
    float*          zsum  = ds2s + (size_t)64 * 8192;             // 16 sub * 8192
    float*          osl   = zsum + (size_t)16 * 8192;             // 80 slots * 4 sub * 8192
    float*          ps    = osl + (size_t)80 * 32768;             // 32,768
    float*          ps2   = ps + 32768;                           // 32,768
    float*          gn1sc = ps2 + 32768;                          // 4,096
    float*          gn1sh = gn1sc + 4096;                         // 4,096
    float*          pooled= gn1sh + 4096;                         // 4,096

    auto OSL = [&](int j) { return osl + (size_t)j * 32768; };

    hipFuncSetAttribute(reinterpret_cast<const void*>(convmfma_kernel),
                        hipFuncAttributeMaxDynamicSharedMemorySize, CONV_LDS_BYTES);

    prepack_kernel<<<dim3(32, 4), 256, 0, stream>>>(ode_w1, ode_w2, ds_w2, ds_w3, Apk, Stab);

    // ---- downsampler (all conv on MFMA; h1 recomputed in-register) ----
    conv1stats_kernel<<<dim3(8, BB), 256, 0, stream>>>(x, ds_w1, ds_b1, ps, ps2);
    gn1fin_kernel<<<16, 256, 0, stream>>>(ps, ps2, ds_n1w, ds_n1b, gn1sc, gn1sh);
    ds2mfma_kernel<<<dim3(64, BB), 256, 0, stream>>>(x, ds_w1, ds_b1, gn1sc, gn1sh,
        Apk + 73728, ds_b2, h2, ds2s);
    ds3mfma_kernel<<<dim3(16, BB), 256, 0, stream>>>(h2, ds2s, ds_n2w, ds_n2b,
        Apk + 139264, ds_b3, z, zb, zsum);

    // ---- ODE: 10 RK4 steps; grid (B, 4) for per-sample XCD affinity ----
    const unsigned short* AP1 = Apk;
    const unsigned short* AP2 = Apk + 36864;
    const float* ST1 = Stab;
    const float* ST2 = Stab + 576;
    const float c6 = 0.1f / 6.0f;
    dim3 cgrid(BB, 4);
    for (int i = 0; i < 10; i++) {
        float t0 = 0.1f * (float)i;
        int j = 8 * i;
        const float* s0 = (i == 0) ? zsum : OSL(j - 1);
        int n0 = (i == 0) ? 16 : 4;
        convmfma_kernel<<<cgrid, 512, CONV_LDS_BYTES, stream>>>(zb, s0, n0, ode_n1w, ode_n1b,
            AP1, ST1, ode_b1, t0, 0.f, 3, z, zb, v, kacc, OSL(j));
        convmfma_kernel<<<cgrid, 512, CONV_LDS_BYTES, stream>>>(v, OSL(j), 4, ode_n2w, ode_n2b,
            AP2, ST2, ode_b2, t0, 0.05f, 0, z, zb, u, kacc, OSL(j + 1));
        convmfma_kernel<<<cgrid, 512, CONV_LDS_BYTES, stream>>>(u, OSL(j + 1), 4, ode_n1w, ode_n1b,
            AP1, ST1, ode_b1, t0 + 0.05f, 0.f, 3, z, zb, v, kacc, OSL(j + 2));
        convmfma_kernel<<<cgrid, 512, CONV_LDS_BYTES, stream>>>(v, OSL(j + 2), 4, ode_n2w, ode_n2b,
            AP2, ST2, ode_b2, t0 + 0.05f, 0.05f, 1, z, zb, u, kacc, OSL(j + 3));
        convmfma_kernel<<<cgrid, 512, CONV_LDS_BYTES, stream>>>(u, OSL(j + 3), 4, ode_n1w, ode_n1b,
            AP1, ST1, ode_b1, t0 + 0.05f, 0.f, 3, z, zb, v, kacc, OSL(j + 4));
        convmfma_kernel<<<cgrid, 512, CONV_LDS_BYTES, stream>>>(v, OSL(j + 4), 4, ode_n2w, ode_n2b,
            AP2, ST2, ode_b2, t0 + 0.05f, 0.1f, 1, z, zb, u, kacc, OSL(j + 5));
        convmfma_kernel<<<cgrid, 512, CONV_LDS_BYTES, stream>>>(u, OSL(j + 5), 4, ode_n1w, ode_n1b,
            AP1, ST1, ode_b1, t0 + 0.1f, 0.f, 3, z, zb, v, kacc, OSL(j + 6));
        convmfma_kernel<<<cgrid, 512, CONV_LDS_BYTES, stream>>>(v, OSL(j + 6), 4, ode_n2w, ode_n2b,
            AP2, ST2, ode_b2, t0 + 0.1f, c6, 2, z, zb, zb, kacc, OSL(j + 7));
    }

    // ---- head ----
    headgap_kernel<<<BB, 256, 0, stream>>>(z, head_nw, head_nb, pooled);
    headfc_kernel<<<3, 256, 0, stream>>>(pooled, head_W, head_b, (float*)d_out);
}

// Round 15
// 2178.080 us; speedup vs baseline: 1.1370x; 1.0374x over previous
//
#include <hip/hip_runtime.h>

#define BB 64   // batch
#define CC 64   // channels

typedef __attribute__((ext_vector_type(8))) short short8;
typedef __attribute__((ext_vector_type(4))) short short4v;
typedef __attribute__((ext_vector_type(4))) float f32x4;

__device__ __forceinline__ float bf2f(unsigned short h) {
    unsigned int u = ((unsigned int)h) << 16;
    float f; __builtin_memcpy(&f, &u, 4); return f;
}
__device__ __forceinline__ unsigned short f2bf(float f) {
    unsigned int u; __builtin_memcpy(&u, &f, 4);
    u += 0x7fffu + ((u >> 16) & 1u);
    return (unsigned short)(u >> 16);
}

// ================= GN1 stats directly from x (recompute conv1) =================
__global__ __launch_bounds__(256) void conv1stats_kernel(const float* __restrict__ x,
    const float* __restrict__ w1, const float* __restrict__ b1,
    float* __restrict__ ps, float* __restrict__ ps2) {
    __shared__ float sw1[576];
    __shared__ float sb1[64];
    __shared__ float xs[10 * 130];
    int tid = threadIdx.x;
    int qq = blockIdx.x;
    int b = blockIdx.y;
    for (int i = tid; i < 576; i += 256) sw1[i] = w1[i];
    if (tid < 64) sb1[tid] = b1[tid];
    const float* xb = x + (size_t)b * 130 * 130;
    int c = tid >> 2, q = tid & 3;
    float s = 0.f, s2 = 0.f;
    for (int sidx = 0; sidx < 2; sidx++) {
        int row0 = (qq * 2 + sidx) * 8;
        __syncthreads();
        for (int i = tid; i < 1300; i += 256) xs[i] = xb[row0 * 130 + i];
        __syncthreads();
        const float* wc = &sw1[c * 9];
        float bc = sb1[c];
        for (int p = q; p < 1024; p += 4) {
            int y = p >> 7, xx = p & 127;
            float v = bc;
#pragma unroll
            for (int ky = 0; ky < 3; ky++)
#pragma unroll
                for (int kx = 0; kx < 3; kx++)
                    v += xs[(y + ky) * 130 + xx + kx] * wc[ky * 3 + kx];
            s += v; s2 += v * v;
        }
    }
    s  += __shfl_xor(s, 1, 64);  s  += __shfl_xor(s, 2, 64);
    s2 += __shfl_xor(s2, 1, 64); s2 += __shfl_xor(s2, 2, 64);
    if (q == 0) {
        ps [(b * 8 + qq) * 64 + c] = s;
        ps2[(b * 8 + qq) * 64 + c] = s2;
    }
}

__global__ __launch_bounds__(256) void gn1fin_kernel(const float* __restrict__ ps,
    const float* __restrict__ ps2, const float* __restrict__ n1w, const float* __restrict__ n1b,
    float* __restrict__ gn1sc, float* __restrict__ gn1sh) {
    int i = blockIdx.x * 256 + threadIdx.x;
    if (i >= BB * CC) return;
    int c = i & 63, b = i >> 6;
    float s = 0.f, s2 = 0.f;
#pragma unroll
    for (int qq = 0; qq < 8; qq++) {
        s  += ps [(b * 8 + qq) * 64 + c];
        s2 += ps2[(b * 8 + qq) * 64 + c];
    }
    float mean = s / 16384.f;
    float var = s2 / 16384.f - mean * mean;
    float rstd = rsqrtf(var + 1e-5f);
    float sc = rstd * n1w[c];
    gn1sc[i] = sc;
    gn1sh[i] = n1b[c] - mean * sc;
}

// ===== weight prepack, chunk-major A: Apk[kc][co][32] bf16 =====
__global__ __launch_bounds__(256) void prepack_kernel(const float* __restrict__ w1,
    const float* __restrict__ w2, const float* __restrict__ dw2,
    const float* __restrict__ dw3, unsigned short* __restrict__ Apk,
    float* __restrict__ Stab) {
    int set = blockIdx.y, kc = blockIdx.x, tid = threadIdx.x;
    int nchunk = (set < 2) ? 18 : 32;
    if (kc < nchunk) {
        const float* w = (set == 0) ? w1 : (set == 1) ? w2 : (set == 2) ? dw2 : dw3;
        size_t off = (set == 0) ? 0 : (set == 1) ? 36864 : (set == 2) ? 73728 : 139264;
        for (int e = tid; e < 2048; e += 256) {
            int co = e >> 5, j = e & 31;
            int k = kc * 32 + j;
            int ci = k & 63;
            int tap = k >> 6;
            float val;
            if (set < 2) val = w[(co * 65 + ci + 1) * 9 + tap];
            else         val = w[((co << 6) + ci) * 16 + tap];
            Apk[off + (size_t)kc * 2048 + e] = f2bf(val);
        }
    }
    if (set < 2 && kc == 0) {
        const float* w = set ? w2 : w1;
        for (int t = tid; t < 576; t += 256) {
            int co = t / 9, tap = t % 9;
            Stab[set * 576 + t] = w[(co * 65) * 9 + tap];
        }
    }
}

// ===== ds2mfma: x -> conv1 -> GN1 -> ReLU (in-register) -> conv4x4/s2 MFMA -> h2 =====
__global__ __launch_bounds__(256) void ds2mfma_kernel(const float* __restrict__ x,
    const float* __restrict__ w1, const float* __restrict__ b1,
    const float* __restrict__ gn1sc, const float* __restrict__ gn1sh,
    const unsigned short* __restrict__ Apk, const float* __restrict__ bias2,
    unsigned short* __restrict__ h2, float* __restrict__ sums_out) {
    __shared__ unsigned short X[2 * 198 * 64];
    __shared__ float xs[8 * 68];
    __shared__ float sw1[576];
    __shared__ float sb1[64], ssc[64], ssh[64], sb2[64];
    __shared__ float sred[4][64], s2red[4][64];
    int tid = threadIdx.x;
    int b = blockIdx.y;
    int bx = blockIdx.x;
    int xh = bx & 1, sy = bx >> 1;
    int lane = tid & 63, w = tid >> 6;
    int colL = lane & 15, quad = lane >> 4;

    for (int i = tid; i < 576; i += 256) sw1[i] = w1[i];
    if (tid < 64) {
        sb1[tid] = b1[tid];
        ssc[tid] = gn1sc[b * 64 + tid];
        ssh[tid] = gn1sh[b * 64 + tid];
        sb2[tid] = bias2[tid];
    }
    {
        const float* xb = x + (size_t)b * 130 * 130;
        for (int i = tid; i < 544; i += 256) {
            int r = i / 68, cc = i % 68;
            int xr = 4 * sy - 1 + r, xcg = 64 * xh - 1 + cc;
            xs[i] = (xr >= 0 && xr < 130 && xcg >= 0 && xcg < 130) ? xb[xr * 130 + xcg] : 0.f;
        }
    }
    __syncthreads();
    {
        int sub = tid & 7;
        float sbr[8], scr[8], shr[8];
#pragma unroll
        for (int e = 0; e < 8; e++) {
            int c = sub * 8 + e;
            sbr[e] = sb1[c]; scr[e] = ssc[c]; shr[e] = ssh[c];
        }
        for (int i = tid; i < 3168; i += 256) {
            int pidx = i >> 3;
            int ir = pidx / 66, ic = pidx - ir * 66;
            int gy = 4 * sy - 1 + ir, gxg = 64 * xh - 1 + ic;
            short8 o;
            if (gy >= 0 && gy < 128 && gxg >= 0 && gxg < 128) {
#pragma unroll
                for (int e = 0; e < 8; e++) {
                    int c = sub * 8 + e;
                    float v = sbr[e];
#pragma unroll
                    for (int ky = 0; ky < 3; ky++)
#pragma unroll
                        for (int kx = 0; kx < 3; kx++)
                            v += xs[(ir + ky) * 68 + ic + kx] * sw1[c * 9 + ky * 3 + kx];
                    o[e] = (short)f2bf(fmaxf(fmaf(v, scr[e], shr[e]), 0.f));
                }
            } else {
#pragma unroll
                for (int e = 0; e < 8; e++) o[e] = 0;
            }
            int p = ic & 1;
            int psx = ir * 33 + (ic >> 1);
            *(short8*)(X + ((p * 198 + psx) << 6) + ((sub ^ (psx & 7)) << 3)) = o;
        }
    }
    __syncthreads();

    int l = w >> 1, oxb = (w & 1) * 16;
    int oxl = oxb + colL;
    f32x4 acc[4] = {};
    for (int kc = 0; kc < 32; ++kc) {
        int tap = kc >> 1;
        int ky = tap >> 2, kx = tap & 3;
        int chgrp = (kc & 1) * 4 + quad;
        int ir = 2 * l + ky;
        int p = kx & 1;
        int psx = ir * 33 + oxl + (kx >> 1);
        short8 bb = *(const short8*)(X + ((p * 198 + psx) << 6) + ((chgrp ^ (psx & 7)) << 3));
        const unsigned short* ap = Apk + (((kc << 6) + colL) << 5) + (quad << 3);
        short8 a0 = *(const short8*)(ap);
        short8 a1 = *(const short8*)(ap + 512);
        short8 a2 = *(const short8*)(ap + 1024);
        short8 a3 = *(const short8*)(ap + 1536);
        acc[0] = __builtin_amdgcn_mfma_f32_16x16x32_bf16(a0, bb, acc[0], 0, 0, 0);
        acc[1] = __builtin_amdgcn_mfma_f32_16x16x32_bf16(a1, bb, acc[1], 0, 0, 0);
        acc[2] = __builtin_amdgcn_mfma_f32_16x16x32_bf16(a2, bb, acc[2], 0, 0, 0);
        acc[3] = __builtin_amdgcn_mfma_f32_16x16x32_bf16(a3, bb, acc[3], 0, 0, 0);
    }

    float sl[16], s2l[16];
#pragma unroll
    for (int i = 0; i < 16; i++) { sl[i] = 0.f; s2l[i] = 0.f; }
    int oy = 2 * sy + l, oxg = xh * 32 + oxl;
#pragma unroll
    for (int mt = 0; mt < 4; ++mt) {
        int co0 = mt * 16 + quad * 4;
        size_t base = ((size_t)((b * 64 + oy) * 64 + oxg)) * 64 + co0;
        short4v o;
#pragma unroll
        for (int r = 0; r < 4; ++r) {
            unsigned short hh = f2bf(acc[mt][r] + sb2[co0 + r]);
            o[r] = (short)hh;
            float f = bf2f(hh);
            sl[mt * 4 + r] += f; s2l[mt * 4 + r] += f * f;
        }
        *(short4v*)(h2 + base) = o;
    }
#pragma unroll
    for (int idx = 0; idx < 16; ++idx) {
        float s = sl[idx], s2 = s2l[idx];
        s += __shfl_xor(s, 1, 64); s += __shfl_xor(s, 2, 64);
        s += __shfl_xor(s, 4, 64); s += __shfl_xor(s, 8, 64);
        s2 += __shfl_xor(s2, 1, 64); s2 += __shfl_xor(s2, 2, 64);
        s2 += __shfl_xor(s2, 4, 64); s2 += __shfl_xor(s2, 8, 64);
        if (colL == 0) {
            int co = (idx >> 2) * 16 + quad * 4 + (idx & 3);
            sred[w][co] = s; s2red[w][co] = s2;
        }
    }
    __syncthreads();
    if (tid < 64) {
        float s = sred[0][tid] + sred[1][tid] + sred[2][tid] + sred[3][tid];
        float s2 = s2red[0][tid] + s2red[1][tid] + s2red[2][tid] + s2red[3][tid];
        sums_out[(size_t)bx * 8192 + b * 64 + tid] = s;
        sums_out[(size_t)bx * 8192 + 4096 + b * 64 + tid] = s2;
    }
}

// ===== ds3mfma: h2(bf16 NHWC) -> GN2+ReLU on load -> conv4x4/s2 MFMA -> z,zb,zsums =====
__global__ __launch_bounds__(256) void ds3mfma_kernel(const unsigned short* __restrict__ h2,
    const float* __restrict__ sums_in, const float* __restrict__ gw, const float* __restrict__ gb,
    const unsigned short* __restrict__ Apk, const float* __restrict__ bias3,
    float* __restrict__ z, unsigned short* __restrict__ zb, float* __restrict__ sums_out) {
    __shared__ unsigned short X[2 * 198 * 64];
    __shared__ float ssc[64], ssh[64], sb3[64];
    __shared__ float sred[4][64], s2red[4][64];
    int tid = threadIdx.x;
    int b = blockIdx.y, sy = blockIdx.x;
    int lane = tid & 63, w = tid >> 6;
    int colL = lane & 15, quad = lane >> 4;

    if (tid < 64) {
        int c = tid;
        float s = 0.f, s2 = 0.f;
        const float* sp = sums_in + b * 64 + c;
        for (int i = 0; i < 64; i++) { s += sp[(size_t)i * 8192]; s2 += sp[(size_t)i * 8192 + 4096]; }
        float mean = s * (1.f / 4096.f);
        float var = fmaxf(s2 * (1.f / 4096.f) - mean * mean, 0.f);
        float sc = rsqrtf(var + 1e-5f) * gw[c];
        ssc[c] = sc;
        ssh[c] = gb[c] - mean * sc;
        sb3[c] = bias3[c];
    }
    __syncthreads();
    {
        int sub = tid & 7;
        float scr[8], shr[8];
#pragma unroll
        for (int e = 0; e < 8; e++) { scr[e] = ssc[sub * 8 + e]; shr[e] = ssh[sub * 8 + e]; }
        for (int i = tid; i < 3168; i += 256) {
            int pidx = i >> 3;
            int ir = pidx / 66, ic = pidx - ir * 66;
            int gy = 4 * sy - 1 + ir, gx = ic - 1;
            short8 o;
            if (gy >= 0 && gy < 64 && gx >= 0 && gx < 64) {
                short8 d = *(const short8*)(h2 + ((size_t)((b * 64 + gy) * 64 + gx)) * 64 + sub * 8);
#pragma unroll
                for (int e = 0; e < 8; e++) {
                    float f = bf2f((unsigned short)d[e]);
                    o[e] = (short)f2bf(fmaxf(fmaf(f, scr[e], shr[e]), 0.f));
                }
            } else {
#pragma unroll
                for (int e = 0; e < 8; e++) o[e] = 0;
            }
            int p = ic & 1;
            int psx = ir * 33 + (ic >> 1);
            *(short8*)(X + ((p * 198 + psx) << 6) + ((sub ^ (psx & 7)) << 3)) = o;
        }
    }
    __syncthreads();

    int l = w >> 1, oxb = (w & 1) * 16;
    int oxl = oxb + colL;
    f32x4 acc[4] = {};
    for (int kc = 0; kc < 32; ++kc) {
        int tap = kc >> 1;
        int ky = tap >> 2, kx = tap & 3;
        int chgrp = (kc & 1) * 4 + quad;
        int ir = 2 * l + ky;
        int p = kx & 1;
        int psx = ir * 33 + oxl + (kx >> 1);
        short8 bb = *(const short8*)(X + ((p * 198 + psx) << 6) + ((chgrp ^ (psx & 7)) << 3));
        const unsigned short* ap = Apk + (((kc << 6) + colL) << 5) + (quad << 3);
        short8 a0 = *(const short8*)(ap);
        short8 a1 = *(const short8*)(ap + 512);
        short8 a2 = *(const short8*)(ap + 1024);
        short8 a3 = *(const short8*)(ap + 1536);
        acc[0] = __builtin_amdgcn_mfma_f32_16x16x32_bf16(a0, bb, acc[0], 0, 0, 0);
        acc[1] = __builtin_amdgcn_mfma_f32_16x16x32_bf16(a1, bb, acc[1], 0, 0, 0);
        acc[2] = __builtin_amdgcn_mfma_f32_16x16x32_bf16(a2, bb, acc[2], 0, 0, 0);
        acc[3] = __builtin_amdgcn_mfma_f32_16x16x32_bf16(a3, bb, acc[3], 0, 0, 0);
    }

    float sl[16], s2l[16];
#pragma unroll
    for (int i = 0; i < 16; i++) { sl[i] = 0.f; s2l[i] = 0.f; }
    int py = 2 * sy + l;
#pragma unroll
    for (int mt = 0; mt < 4; ++mt) {
        int co0 = mt * 16 + quad * 4;
        size_t base = ((size_t)((b << 10) + py * 32 + oxl)) * 64 + co0;
        f32x4 zv;
        short4v o;
#pragma unroll
        for (int r = 0; r < 4; ++r) {
            float val = acc[mt][r] + sb3[co0 + r];
            zv[r] = val;
            unsigned short hh = f2bf(val);
            o[r] = (short)hh;
            float f = bf2f(hh);
            sl[mt * 4 + r] += f; s2l[mt * 4 + r] += f * f;
        }
        *(f32x4*)(z + base) = zv;
        *(short4v*)(zb + base) = o;
    }
#pragma unroll
    for (int idx = 0; idx < 16; ++idx) {
        float s = sl[idx], s2 = s2l[idx];
        s += __shfl_xor(s, 1, 64); s += __shfl_xor(s, 2, 64);
        s += __shfl_xor(s, 4, 64); s += __shfl_xor(s, 8, 64);
        s2 += __shfl_xor(s2, 1, 64); s2 += __shfl_xor(s2, 2, 64);
        s2 += __shfl_xor(s2, 4, 64); s2 += __shfl_xor(s2, 8, 64);
        if (colL == 0) {
            int co = (idx >> 2) * 16 + quad * 4 + (idx & 3);
            sred[w][co] = s; s2red[w][co] = s2;
        }
    }
    __syncthreads();
    if (tid < 64) {
        float s = sred[0][tid] + sred[1][tid] + sred[2][tid] + sred[3][tid];
        float s2 = s2red[0][tid] + s2red[1][tid] + s2red[2][tid] + s2red[3][tid];
        sums_out[(size_t)sy * 8192 + b * 64 + tid] = s;
        sums_out[(size_t)sy * 8192 + 4096 + b * 64 + tid] = s2;
    }
}

// ==================== MFMA implicit-GEMM ODE conv (3x3 pad1, 64+t -> 64) ============
// grid (64 samples, 4 strips): XCD-affinity mapping. A in LDS (APAD=40 pad: 2-way
// banks); staging + epilogue operands prefetched. kacc bf16; stats via sub-slots.
#define APAD 40
#define CONV_LDS_BYTES 142592
__global__ __launch_bounds__(512, 2) void convmfma_kernel(
    const unsigned short* __restrict__ uin, const float* __restrict__ sums_in, int nsub,
    const float* __restrict__ gw, const float* __restrict__ gb,
    const unsigned short* __restrict__ Apk, const float* __restrict__ stab,
    const float* __restrict__ bias, float t, float aa, int mode,
    float* __restrict__ z, const unsigned short* __restrict__ zbin,
    unsigned short* __restrict__ uout, unsigned short* __restrict__ kacc,
    float* __restrict__ sums_out)
{
    extern __shared__ unsigned short smem[];
    unsigned short* Aw = smem;                    // 18*64*APAD = 46080 shorts (92160 B)
    unsigned short* X  = smem + 46080;            // 21760 shorts (10*34*64)
    float* fp    = (float*)(smem + 67840);
    float* ssc   = fp;        float* ssh   = fp + 64;
    float* tS    = fp + 128;  float* trow0 = fp + 192;  float* trow2 = fp + 256;
    float* tcol0 = fp + 320;  float* tcol2 = fp + 384;
    float* tc00  = fp + 448;  float* tc02  = fp + 512;
    float* tc20  = fp + 576;  float* tc22  = fp + 640;
    float* sred  = fp + 704;             // [8][64]
    float* s2red = fp + 1216;            // [8][64]

    int tid = threadIdx.x;
    int b = blockIdx.x, strip = blockIdx.y;
    int y0 = strip * 8;
    int lane = tid & 63, w = tid >> 6;
    int colL = lane & 15, quad = lane >> 4;
    int sub = tid & 7;

    short8 dpre[5];
    int pr[5], pxc[5];
    bool pok[5];
#pragma unroll
    for (int it = 0; it < 5; ++it) {
        int pidx = (tid >> 3) + it * 64;
        int r = pidx >> 5, xc = pidx & 31;
        int gy = y0 - 1 + r;
        pr[it] = r; pxc[it] = xc;
        pok[it] = (gy >= 0 && gy <= 31);
        if (pok[it])
            dpre[it] = *(const short8*)(uin + ((size_t)((b << 10) + gy * 32 + xc)) * 64 + sub * 8);
    }

    {
        f32x4 zz = 0.f;
        for (int i = tid; i < 2720; i += 512) ((f32x4*)X)[i] = zz;
    }
    for (int i = tid; i < 4608; i += 512) {
        int row = i >> 2, part = i & 3;
        *(f32x4*)(Aw + row * APAD + part * 8) = ((const f32x4*)Apk)[i];
    }

    if (tid < 64) {
        int c = tid;
        float s = 0.f, s2 = 0.f;
        const float* sp = sums_in + b * 64 + c;
        for (int i = 0; i < nsub; i++) { s += sp[(size_t)i * 8192]; s2 += sp[(size_t)i * 8192 + 4096]; }
        float mean = s * (1.f / 1024.f);
        float var = fmaxf(s2 * (1.f / 1024.f) - mean * mean, 0.f);
        float sc = rsqrtf(var + 1e-5f) * gw[c];
        ssc[c] = sc;
        ssh[c] = gb[c] - mean * sc;
    } else if (tid < 128) {
        int co = tid - 64;
        float w0[9];
#pragma unroll
        for (int k = 0; k < 9; k++) w0[k] = stab[co * 9 + k] * t;
        tS[co] = bias[co] + w0[0]+w0[1]+w0[2]+w0[3]+w0[4]+w0[5]+w0[6]+w0[7]+w0[8];
        trow0[co] = w0[0] + w0[1] + w0[2];
        trow2[co] = w0[6] + w0[7] + w0[8];
        tcol0[co] = w0[0] + w0[3] + w0[6];
        tcol2[co] = w0[2] + w0[5] + w0[8];
        tc00[co] = w0[0]; tc02[co] = w0[2]; tc20[co] = w0[6]; tc22[co] = w0[8];
    }
    __syncthreads();

    {
        float scr[8], shr[8];
#pragma unroll
        for (int e = 0; e < 8; e++) { scr[e] = ssc[sub * 8 + e]; shr[e] = ssh[sub * 8 + e]; }
#pragma unroll
        for (int it = 0; it < 5; ++it) {
            if (!pok[it]) continue;
            short8 d = dpre[it];
            short8 o;
#pragma unroll
            for (int e = 0; e < 8; e++) {
                float f = bf2f((unsigned short)d[e]);
                o[e] = (short)f2bf(fmaxf(fmaf(f, scr[e], shr[e]), 0.f));
            }
            int psx = pr[it] * 34 + pxc[it] + 1;
            *(short8*)(X + (psx << 6) + ((sub ^ (psx & 7)) << 3)) = o;
        }
    }

    int py = y0 + w;
    short4v preZb[8], preK[8];
    f32x4 preZ[8];
    if (mode == 2) {
#pragma unroll
        for (int nt = 0; nt < 2; ++nt)
#pragma unroll
            for (int mt = 0; mt < 4; ++mt) {
                size_t base = ((size_t)((b << 10) + py * 32 + nt * 16 + colL)) * 64 + mt * 16 + quad * 4;
                preK[nt * 4 + mt] = *(const short4v*)(kacc + base);
                preZ[nt * 4 + mt] = *(const f32x4*)(z + base);
            }
    } else if (mode != 3) {
#pragma unroll
        for (int nt = 0; nt < 2; ++nt)
#pragma unroll
            for (int mt = 0; mt < 4; ++mt) {
                size_t base = ((size_t)((b << 10) + py * 32 + nt * 16 + colL)) * 64 + mt * 16 + quad * 4;
                preZb[nt * 4 + mt] = *(const short4v*)(zbin + base);
                if (mode == 1) preK[nt * 4 + mt] = *(const short4v*)(kacc + base);
            }
    }
    __syncthreads();

    f32x4 acc[4][2] = {};
    for (int kc = 0; kc < 18; ++kc) {
        int tap = kc >> 1;
        int dy = tap / 3, dx = tap % 3;
        int chgrp = (kc & 1) * 4 + quad;
        int ps0 = (w + dy) * 34 + colL + dx;
        int ps1 = ps0 + 16;
        short8 bb0 = *(const short8*)(X + (ps0 << 6) + ((chgrp ^ (ps0 & 7)) << 3));
        short8 bb1 = *(const short8*)(X + (ps1 << 6) + ((chgrp ^ (ps1 & 7)) << 3));
        const unsigned short* ap = Aw + ((kc << 6) + colL) * APAD + (quad << 3);
        short8 a0 = *(const short8*)(ap);
        short8 a1 = *(const short8*)(ap + 16 * APAD);
        short8 a2 = *(const short8*)(ap + 32 * APAD);
        short8 a3 = *(const short8*)(ap + 48 * APAD);
        acc[0][0] = __builtin_amdgcn_mfma_f32_16x16x32_bf16(a0, bb0, acc[0][0], 0, 0, 0);
        acc[0][1] = __builtin_amdgcn_mfma_f32_16x16x32_bf16(a0, bb1, acc[0][1], 0, 0, 0);
        acc[1][0] = __builtin_amdgcn_mfma_f32_16x16x32_bf16(a1, bb0, acc[1][0], 0, 0, 0);
        acc[1][1] = __builtin_amdgcn_mfma_f32_16x16x32_bf16(a1, bb1, acc[1][1], 0, 0, 0);
        acc[2][0] = __builtin_amdgcn_mfma_f32_16x16x32_bf16(a2, bb0, acc[2][0], 0, 0, 0);
        acc[2][1] = __builtin_amdgcn_mfma_f32_16x16x32_bf16(a2, bb1, acc[2][1], 0, 0, 0);
        acc[3][0] = __builtin_amdgcn_mfma_f32_16x16x32_bf16(a3, bb0, acc[3][0], 0, 0, 0);
        acc[3][1] = __builtin_amdgcn_mfma_f32_16x16x32_bf16(a3, bb1, acc[3][1], 0, 0, 0);
    }

    float sl[16], s2l[16];
#pragma unroll
    for (int i = 0; i < 16; i++) { sl[i] = 0.f; s2l[i] = 0.f; }
    bool by0 = (py == 0), by1 = (py == 31);
#pragma unroll
    for (int nt = 0; nt < 2; ++nt) {
        int px = nt * 16 + colL;
        bool bx0 = (px == 0), bx1 = (px == 31);
#pragma unroll
        for (int mt = 0; mt < 4; ++mt) {
            int co0 = mt * 16 + quad * 4;
            int pi = nt * 4 + mt;
            float vout[4];
#pragma unroll
            for (int r = 0; r < 4; ++r) {
                int co = co0 + r;
                float val = acc[mt][nt][r] + tS[co];
                if (by0) { val -= trow0[co]; if (bx0) val += tc00[co]; if (bx1) val += tc02[co]; }
                if (by1) { val -= trow2[co]; if (bx0) val += tc20[co]; if (bx1) val += tc22[co]; }
                if (bx0) val -= tcol0[co];
                if (bx1) val -= tcol2[co];
                vout[r] = val;
            }
            size_t base = ((size_t)((b << 10) + py * 32 + px)) * 64 + co0;
            if (mode == 3) {
                short4v o;
#pragma unroll
                for (int r = 0; r < 4; ++r) {
                    unsigned short hh = f2bf(vout[r]);
                    o[r] = (short)hh;
                    float f = bf2f(hh);
                    sl[mt * 4 + r] += f; s2l[mt * 4 + r] += f * f;
                }
                *(short4v*)(uout + base) = o;
            } else if (mode == 2) {
                f32x4 zv = preZ[pi];
                short4v kv = preK[pi];
                short4v o;
#pragma unroll
                for (int r = 0; r < 4; ++r) {
                    float zn = zv[r] + aa * (bf2f((unsigned short)kv[r]) + vout[r]);
                    zv[r] = zn;
                    unsigned short hh = f2bf(zn);
                    o[r] = (short)hh;
                    float f = bf2f(hh);
                    sl[mt * 4 + r] += f; s2l[mt * 4 + r] += f * f;
                }
                *(f32x4*)(z + base) = zv;
                *(short4v*)(uout + base) = o;
            } else {
                short4v zs = preZb[pi];
                short4v ko, o;
                if (mode == 1) {
                    short4v kv = preK[pi];
#pragma unroll
                    for (int r = 0; r < 4; ++r)
                        ko[r] = (short)f2bf(bf2f((unsigned short)kv[r]) + 2.f * vout[r]);
                } else {
#pragma unroll
                    for (int r = 0; r < 4; ++r) ko[r] = (short)f2bf(vout[r]);
                }
                *(short4v*)(kacc + base) = ko;
#pragma unroll
                for (int r = 0; r < 4; ++r) {
                    float zf = bf2f((unsigned short)zs[r]);
                    unsigned short hh = f2bf(zf + aa * vout[r]);
                    o[r] = (short)hh;
                    float f = bf2f(hh);
                    sl[mt * 4 + r] += f; s2l[mt * 4 + r] += f * f;
                }
                *(short4v*)(uout + base) = o;
            }
        }
    }
#pragma unroll
    for (int idx = 0; idx < 16; ++idx) {
        float s = sl[idx], s2 = s2l[idx];
        s += __shfl_xor(s, 1, 64); s += __shfl_xor(s, 2, 64);
        s += __shfl_xor(s, 4, 64); s += __shfl_xor(s, 8, 64);
        s2 += __shfl_xor(s2, 1, 64); s2 += __shfl_xor(s2, 2, 64);
        s2 += __shfl_xor(s2, 4, 64); s2 += __shfl_xor(s2, 8, 64);
        if (colL == 0) {
            int co = (idx >> 2) * 16 + quad * 4 + (idx & 3);
            sred[w * 64 + co] = s; s2red[w * 64 + co] = s2;
        }
    }
    __syncthreads();
    if (tid < 64) {
        float s = 0.f, s2 = 0.f;
#pragma unroll
        for (int i = 0; i < 8; i++) { s += sred[i * 64 + tid]; s2 += s2red[i * 64 + tid]; }
        sums_out[(size_t)strip * 8192 + b * 64 + tid] = s;
        sums_out[(size_t)strip * 8192 + 4096 + b * 64 + tid] = s2;
    }
}

// ================= head: GN + ReLU + GAP from NHWC z =================
__global__ __launch_bounds__(256) void headgap_kernel(const float* __restrict__ z,
    const float* __restrict__ w, const float* __restrict__ b, float* __restrict__ pooled) {
    __shared__ float r1[4][64], r2[4][64];
    __shared__ float scs[64], shs[64];
    int bq = blockIdx.x, tid = threadIdx.x;
    int c = tid & 63, g = tid >> 6;
    float s = 0.f, s2 = 0.f;
    for (int p = g; p < 1024; p += 4) {
        float v = z[((size_t)((bq << 10) + p)) * 64 + c];
        s += v; s2 += v * v;
    }
    r1[g][c] = s; r2[g][c] = s2;
    __syncthreads();
    if (tid < 64) {
        float ts = r1[0][tid] + r1[1][tid] + r1[2][tid] + r1[3][tid];
        float ts2 = r2[0][tid] + r2[1][tid] + r2[2][tid] + r2[3][tid];
        float mean = ts / 1024.f;
        float var = fmaxf(ts2 / 1024.f - mean * mean, 0.f);
        float sc = rsqrtf(var + 1e-5f) * w[tid];
        scs[tid] = sc;
        shs[tid] = b[tid] - mean * sc;
    }
    __syncthreads();
    float sc = scs[c], sh = shs[c];
    float r = 0.f;
    for (int p = g; p < 1024; p += 4)
        r += fmaxf(fmaf(z[((size_t)((bq << 10) + p)) * 64 + c], sc, sh), 0.f);
    r1[g][c] = r;
    __syncthreads();
    if (tid < 64)
        pooled[bq * 64 + tid] = (r1[0][tid] + r1[1][tid] + r1[2][tid] + r1[3][tid]) / 1024.f;
}

__global__ __launch_bounds__(256) void headfc_kernel(const float* __restrict__ pooled,
    const float* __restrict__ W, const float* __restrict__ bias, float* __restrict__ out) {
    int i = blockIdx.x * 256 + threadIdx.x;
    if (i < 640) {
        int b = i / 10, j = i % 10;
        float a = bias[j];
        const float* p = pooled + b * 64;
        const float* wj = W + j * 64;
#pragma unroll 8
        for (int c = 0; c < 64; c++) a += p[c] * wj[c];
        out[i] = a;
    }
}

extern "C" void kernel_launch(void* const* d_in, const int* in_sizes, int n_in,
                              void* d_out, int out_size, void* d_ws, size_t ws_size,
                              hipStream_t stream) {
    const float* x      = (const float*)d_in[0];
    const float* ds_w1  = (const float*)d_in[1];
    const float* ds_b1  = (const float*)d_in[2];
    const float* ds_n1w = (const float*)d_in[3];
    const float* ds_n1b = (const float*)d_in[4];
    const float* ds_w2  = (const float*)d_in[5];
    const float* ds_b2  = (const float*)d_in[6];
    const float* ds_n2w = (const float*)d_in[7];
    const float* ds_n2b = (const float*)d_in[8];
    const float* ds_w3  = (const float*)d_in[9];
    const float* ds_b3  = (const float*)d_in[10];
    const float* ode_w1 = (const float*)d_in[11];
    const float* ode_b1 = (const float*)d_in[12];
    const float* ode_n1w= (const float*)d_in[13];
    const float* ode_n1b= (const float*)d_in[14];
    const float* ode_w2 = (const float*)d_in[15];
    const float* ode_b2 = (const float*)d_in[16];
    const float* ode_n2w= (const float*)d_in[17];
    const float* ode_n2b= (const float*)d_in[18];
    const float* head_nw= (const float*)d_in[19];
    const float* head_nb= (const float*)d_in[20];
    const float* head_W = (const float*)d_in[21];
    const float* head_b = (const float*)d_in[22];

    const size_t NZ = (size_t)BB * CC * 32 * 32;   // 4,194,304
    float* ws = (float*)d_ws;
    float*          z     = ws;                                   // NZ fp32 NHWC
    unsigned short* zb    = (unsigned short*)(ws + NZ);           // NZ bf16
    unsigned short* u     = (unsigned short*)(ws + 3 * NZ / 2);   // NZ bf16
    unsigned short* v     = (unsigned short*)(ws + 2 * NZ);       // NZ bf16
    unsigned short* kacc  = (unsigned short*)(ws + 5 * NZ / 2);   // NZ bf16
    unsigned short* h2    = u;   // [B,64,64,64] NHWC bf16 spans [1.5NZ, 3.5NZ) fl, dead by ODE
    float*          apf   = ws + 7 * NZ / 2;
    unsigned short* Apk   = (unsigned short*)apf;                 // 204,800 shorts
    float*          Stab  = apf + 102400;                         // 1,152
    float*          ds2s  = Stab + 1152;                          // 64 sub * 8192
    float*          zsum  = ds2s + (size_t)64 * 8192;             // 16 sub * 8192
    float*          osl   = zsum + (size_t)16 * 8192;             // 80 slots * 4 sub * 8192
    float*          ps    = osl + (size_t)80 * 32768;             // 32,768
    float*          ps2   = ps + 32768;                           // 32,768
    float*          gn1sc = ps2 + 32768;                          // 4,096
    float*          gn1sh = gn1sc + 4096;                         // 4,096
    float*          pooled= gn1sh + 4096;                         // 4,096

    auto OSL = [&](int j) { return osl + (size_t)j * 32768; };

    hipFuncSetAttribute(reinterpret_cast<const void*>(convmfma_kernel),
                        hipFuncAttributeMaxDynamicSharedMemorySize, CONV_LDS_BYTES);

    prepack_kernel<<<dim3(32, 4), 256, 0, stream>>>(ode_w1, ode_w2, ds_w2, ds_w3, Apk, Stab);

    // ---- downsampler (all conv on MFMA; h1 recomputed in-register) ----
    conv1stats_kernel<<<dim3(8, BB), 256, 0, stream>>>(x, ds_w1, ds_b1, ps, ps2);
    gn1fin_kernel<<<16, 256, 0, stream>>>(ps, ps2, ds_n1w, ds_n1b, gn1sc, gn1sh);
    ds2mfma_kernel<<<dim3(64, BB), 256, 0, stream>>>(x, ds_w1, ds_b1, gn1sc, gn1sh,
        Apk + 73728, ds_b2, h2, ds2s);
    ds3mfma_kernel<<<dim3(16, BB), 256, 0, stream>>>(h2, ds2s, ds_n2w, ds_n2b,
        Apk + 139264, ds_b3, z, zb, zsum);

    // ---- ODE: 10 RK4 steps; grid (B, 4) for per-sample XCD affinity ----
    const unsigned short* AP1 = Apk;
    const unsigned short* AP2 = Apk + 36864;
    const float* ST1 = Stab;
    const float* ST2 = Stab + 576;
    const float c6 = 0.1f / 6.0f;
    dim3 cgrid(BB, 4);
    for (int i = 0; i < 10; i++) {
        float t0 = 0.1f * (float)i;
        int j = 8 * i;
        const float* s0 = (i == 0) ? zsum : OSL(j - 1);
        int n0 = (i == 0) ? 16 : 4;
        convmfma_kernel<<<cgrid, 512, CONV_LDS_BYTES, stream>>>(zb, s0, n0, ode_n1w, ode_n1b,
            AP1, ST1, ode_b1, t0, 0.f, 3, z, zb, v, kacc, OSL(j));
        convmfma_kernel<<<cgrid, 512, CONV_LDS_BYTES, stream>>>(v, OSL(j), 4, ode_n2w, ode_n2b,
            AP2, ST2, ode_b2, t0, 0.05f, 0, z, zb, u, kacc, OSL(j + 1));
        convmfma_kernel<<<cgrid, 512, CONV_LDS_BYTES, stream>>>(u, OSL(j + 1), 4, ode_n1w, ode_n1b,
            AP1, ST1, ode_b1, t0 + 0.05f, 0.f, 3, z, zb, v, kacc, OSL(j + 2));
        convmfma_kernel<<<cgrid, 512, CONV_LDS_BYTES, stream>>>(v, OSL(j + 2), 4, ode_n2w, ode_n2b,
            AP2, ST2, ode_b2, t0 + 0.05f, 0.05f, 1, z, zb, u, kacc, OSL(j + 3));
        convmfma_kernel<<<cgrid, 512, CONV_LDS_BYTES, stream>>>(u, OSL(j + 3), 4, ode_n1w, ode_n1b,
            AP1, ST1, ode_b1, t0 + 0.05f, 0.f, 3, z, zb, v, kacc, OSL(j + 4));
        convmfma_kernel<<<cgrid, 512, CONV_LDS_BYTES, stream>>>(v, OSL(j + 4), 4, ode_n2w, ode_n2b,
            AP2, ST2, ode_b2, t0 + 0.05f, 0.1f, 1, z, zb, u, kacc, OSL(j + 5));
        convmfma_kernel<<<cgrid, 512, CONV_LDS_BYTES, stream>>>(u, OSL(j + 5), 4, ode_n1w, ode_n1b,
            AP1, ST1, ode_b1, t0 + 0.1f, 0.f, 3, z, zb, v, kacc, OSL(j + 6));
        convmfma_kernel<<<cgrid, 512, CONV_LDS_BYTES, stream>>>(v, OSL(j + 6), 4, ode_n2w, ode_n2b,
            AP2, ST2, ode_b2, t0 + 0.1f, c6, 2, z, zb, zb, kacc, OSL(j + 7));
    }

    // ---- head ----
    headgap_kernel<<<BB, 256, 0, stream>>>(z, head_nw, head_nb, pooled);
    headfc_kernel<<<3, 256, 0, stream>>>(pooled, head_W, head_b, (float*)d_out);
}